// Round 13
// baseline (365.031 us; speedup 1.0000x reference)
//
#include <hip/hip_runtime.h>
#include <math.h>

#define NLAYER 2
#define DMODEL 256
#define DINNER 512
#define DSTATE 16
#define DTRANK 16
#define DCONV  4
#define BB     4
#define LL     2048
#define BL     (BB*LL)
#define NCHUNK 64
#define LC     (LL/NCHUNK)          // 32
#define NREC   (BB*DINNER*DSTATE)   // 32768
#define VOCAB  256
#define XDP    128                  // padded x_dbl row width (48 real cols)

typedef __attribute__((ext_vector_type(8))) short short8;   // 8 bf16 (4 VGPRs)
typedef __attribute__((ext_vector_type(4))) float f32x4;    // 4 fp32 acc

__device__ __forceinline__ float sigmoidf_(float x) { return 1.0f / (1.0f + __expf(-x)); }

// fp32 -> bf16 round-to-nearest-even (bit pattern) and back
__device__ __forceinline__ unsigned f2bf(float a) {
    unsigned u = __builtin_bit_cast(unsigned, a);
    return (u + 0x7fffu + ((u >> 16) & 1u)) >> 16;
}
__device__ __forceinline__ float bf2f(unsigned h) {
    return __builtin_bit_cast(float, h << 16);
}

// ---------------- embedding -> bf16 hi|lo table [VOCAB][2*DMODEL] ----------------
__global__ __launch_bounds__(256) void k_cvt_emb(const float* __restrict__ emb,
                                                 ushort* __restrict__ embf) {
    const int v = blockIdx.x;
    const int c = threadIdx.x;
    float s = emb[(size_t)v * DMODEL + c];
    unsigned hi = f2bf(s);
    unsigned lo = f2bf(s - bf2f(hi));
    embf[(size_t)v * (2 * DMODEL) + c] = (ushort)hi;
    embf[(size_t)v * (2 * DMODEL) + DMODEL + c] = (ushort)lo;
}

// ---------------- weight fp32 [K,N] -> frag bf16 hi/lo ----------------
// frag layout: [N/16][2K/32][64][8]; lane l holds B[kf*32+(l>>4)*8+j][nf*16+(l&15)]
template<int K>
__global__ __launch_bounds__(256) void k_cvt_w(const float* __restrict__ W,
                                               ushort* __restrict__ F, int N) {
    constexpr int NKF = K / 32;
    const int t = blockIdx.x * 256 + threadIdx.x;
    const int l = t & 63;
    const int cid = t >> 6;
    const int kf = cid % NKF;
    const int nf = cid / NKF;
    const int col = nf * 16 + (l & 15);
    const int k0 = kf * 32 + (l >> 4) * 8;
    float s[8];
#pragma unroll
    for (int j = 0; j < 8; ++j) s[j] = W[(size_t)(k0 + j) * N + col];
    unsigned hi[8], lo[8];
#pragma unroll
    for (int j = 0; j < 8; ++j) {
        hi[j] = f2bf(s[j]);
        lo[j] = f2bf(s[j] - bf2f(hi[j]));
    }
    uint4 ph = make_uint4(hi[0] | (hi[1] << 16), hi[2] | (hi[3] << 16),
                          hi[4] | (hi[5] << 16), hi[6] | (hi[7] << 16));
    uint4 pl = make_uint4(lo[0] | (lo[1] << 16), lo[2] | (lo[3] << 16),
                          lo[4] | (lo[5] << 16), lo[6] | (lo[7] << 16));
    size_t ohi = ((size_t)nf * (2 * NKF) + kf) * 512 + l * 8;
    *(uint4*)&F[ohi] = ph;
    *(uint4*)&F[ohi + (size_t)NKF * 512] = pl;
}

// ---------------- w_xp fp32 [K,48] -> frag bf16 hi/lo padded to 128 cols ----------------
template<int K>  // K = DINNER
__global__ __launch_bounds__(256) void k_cvt_wxp(const float* __restrict__ W,
                                                 ushort* __restrict__ F) {
    constexpr int NKF = K / 32;        // 16
    const int t = blockIdx.x * 256 + threadIdx.x;
    const int l = t & 63;
    const int cid = t >> 6;            // 0 .. 8*NKF-1
    const int kf = cid % NKF;
    const int nf = cid / NKF;          // 0..7
    const int col = nf * 16 + (l & 15);
    const int k0 = kf * 32 + (l >> 4) * 8;
    float s[8];
#pragma unroll
    for (int j = 0; j < 8; ++j)
        s[j] = (col < 48) ? W[(size_t)(k0 + j) * 48 + col] : 0.f;
    unsigned hi[8], lo[8];
#pragma unroll
    for (int j = 0; j < 8; ++j) {
        hi[j] = f2bf(s[j]);
        lo[j] = f2bf(s[j] - bf2f(hi[j]));
    }
    uint4 ph = make_uint4(hi[0] | (hi[1] << 16), hi[2] | (hi[3] << 16),
                          hi[4] | (hi[5] << 16), hi[6] | (hi[7] << 16));
    uint4 pl = make_uint4(lo[0] | (lo[1] << 16), lo[2] | (lo[3] << 16),
                          lo[4] | (lo[5] << 16), lo[6] | (lo[7] << 16));
    size_t ohi = ((size_t)nf * (2 * NKF) + kf) * 512 + l * 8;
    *(uint4*)&F[ohi] = ph;
    *(uint4*)&F[ohi + (size_t)NKF * 512] = pl;
}

// ---------------- bf16 MFMA GEMM: A row-major bf16 [M][KE] (per-lane gather), B frag ----------------
template<int SPLITK, bool IDS>
__global__ __launch_bounds__(256) void k_mgemm(const ushort* __restrict__ A,
                                               const ushort* __restrict__ Bf,
                                               float* __restrict__ C,
                                               int M, int N, int KE,
                                               const int* __restrict__ ids) {
    __shared__ __align__(16) ushort As[8 * 512];
    __shared__ __align__(16) ushort Bs[8 * 512];
    const int tid = threadIdx.x;
    const int w = tid >> 6, lane = tid & 63;
    const int n0 = blockIdx.x * 128, m0 = blockIdx.y * 128;
    const int nkf = KE >> 5;
    const int KT = nkf / SPLITK;
    const int kt0 = blockIdx.z * KT;
    const int wm = w & 1, wn = w >> 1;
    const int c0 = 2 * w, c1 = c0 + 1;

    f32x4 acc[4][4] = {};

    int row0 = m0 + c0 * 16 + (lane & 15);
    int row1 = m0 + c1 * 16 + (lane & 15);
    if (IDS) { row0 = ids[row0]; row1 = ids[row1]; }
    const ushort* Ap0 = A + (size_t)row0 * KE + (lane >> 4) * 8;
    const ushort* Ap1 = A + (size_t)row1 * KE + (lane >> 4) * 8;
    const ushort* Bb0 = Bf + ((size_t)(n0 / 16 + c0) * nkf) * 512 + lane * 8;
    const ushort* Bb1 = Bf + ((size_t)(n0 / 16 + c1) * nkf) * 512 + lane * 8;
    ushort* As0 = As + c0 * 512 + lane * 8;
    ushort* As1 = As + c1 * 512 + lane * 8;
    ushort* Bs0 = Bs + c0 * 512 + lane * 8;
    ushort* Bs1 = Bs + c1 * 512 + lane * 8;

    for (int kt = kt0; kt < kt0 + KT; ++kt) {
        __builtin_amdgcn_global_load_lds((const __attribute__((address_space(1))) void*)(Ap0 + kt * 32),
                                         (__attribute__((address_space(3))) void*)As0, 16, 0, 0);
        __builtin_amdgcn_global_load_lds((const __attribute__((address_space(1))) void*)(Ap1 + kt * 32),
                                         (__attribute__((address_space(3))) void*)As1, 16, 0, 0);
        __builtin_amdgcn_global_load_lds((const __attribute__((address_space(1))) void*)(Bb0 + (size_t)kt * 512),
                                         (__attribute__((address_space(3))) void*)Bs0, 16, 0, 0);
        __builtin_amdgcn_global_load_lds((const __attribute__((address_space(1))) void*)(Bb1 + (size_t)kt * 512),
                                         (__attribute__((address_space(3))) void*)Bs1, 16, 0, 0);
        __syncthreads();
        short8 av[4], bv[4];
#pragma unroll
        for (int i = 0; i < 4; ++i)
            av[i] = *(const short8*)&As[(wm * 4 + i) * 512 + lane * 8];
#pragma unroll
        for (int i = 0; i < 4; ++i)
            bv[i] = *(const short8*)&Bs[(wn * 4 + i) * 512 + lane * 8];
#pragma unroll
        for (int mi = 0; mi < 4; ++mi)
#pragma unroll
            for (int ni = 0; ni < 4; ++ni)
                acc[mi][ni] = __builtin_amdgcn_mfma_f32_16x16x32_bf16(av[mi], bv[ni],
                                                                      acc[mi][ni], 0, 0, 0);
        __syncthreads();
    }

    // C/D layout (m89-verified): col = lane&15, row = (lane>>4)*4 + reg
    float* Cw = C + (size_t)blockIdx.z * ((size_t)M * N);
    const int r0 = (lane >> 4) * 4, cc = lane & 15;
#pragma unroll
    for (int mi = 0; mi < 4; ++mi)
#pragma unroll
        for (int r = 0; r < 4; ++r) {
            const int row = m0 + wm * 64 + mi * 16 + r0 + r;
            float* crow = &Cw[(size_t)row * N + n0 + wn * 64 + cc];
#pragma unroll
            for (int ni = 0; ni < 4; ++ni) crow[ni * 16] = acc[mi][ni][r];
        }
}

// sum 4 M*N slabs; TOBF: also write bf16 hi|lo row-major [BL][2*DMODEL]
template<bool TOBF>
__global__ __launch_bounds__(256) void k_red4(const float* __restrict__ p,
                                              float* __restrict__ o,
                                              ushort* __restrict__ xb, int n4) {
    int i = blockIdx.x * 256 + threadIdx.x;
    const float4* p4 = (const float4*)p;
    float4 a = p4[i], b = p4[i + n4], c = p4[i + 2 * n4], d = p4[i + 3 * n4];
    float4 r = make_float4(a.x + b.x + c.x + d.x, a.y + b.y + c.y + d.y,
                           a.z + b.z + c.z + d.z, a.w + b.w + c.w + d.w);
    if (TOBF) {
        const int e0 = i * 4;
        const int bl = e0 >> 8;
        const int cl = e0 & 255;
        float s[4] = {r.x, r.y, r.z, r.w};
        unsigned hi[4], lo[4];
#pragma unroll
        for (int j = 0; j < 4; ++j) {
            hi[j] = f2bf(s[j]);
            lo[j] = f2bf(s[j] - bf2f(hi[j]));
        }
        *(uint2*)&xb[(size_t)bl * 512 + cl] =
            make_uint2(hi[0] | (hi[1] << 16), hi[2] | (hi[3] << 16));
        *(uint2*)&xb[(size_t)bl * 512 + 256 + cl] =
            make_uint2(lo[0] | (lo[1] << 16), lo[2] | (lo[3] << 16));
    } else {
        ((float4*)o)[i] = r;
    }
}

// ---------------- conv + SiLU: u fp32 [BL][512] + ub bf16 hi|lo [BL][1024] ----------------
// thread handles 2 consecutive channels of one token; grid = BL blocks x 256.
__global__ __launch_bounds__(256) void k_conv(const float* __restrict__ xz,
                                              const float* __restrict__ cw,
                                              const float* __restrict__ cb,
                                              float* __restrict__ u,
                                              ushort* __restrict__ ub) {
    const int idx = blockIdx.x * 256 + threadIdx.x;   // over BL*256
    const int bl = idx >> 8;
    const int c0 = (idx & 255) * 2;
    const int l  = bl & (LL - 1);
    float4 cwA = *(const float4*)&cw[c0 * 4];
    float4 cwB = *(const float4*)&cw[c0 * 4 + 4];
    float2 cbv = *(const float2*)&cb[c0];
    float aA = cbv.x, aB = cbv.y;
#pragma unroll
    for (int k = 0; k < DCONV; ++k) {
        int t = l - (DCONV - 1) + k;
        if (t >= 0) {
            float2 xv = *(const float2*)&xz[(size_t)(bl - (DCONV - 1) + k) * 2 * DINNER + c0];
            aA = fmaf(((const float*)&cwA)[k], xv.x, aA);
            aB = fmaf(((const float*)&cwB)[k], xv.y, aB);
        }
    }
    float uA = aA * sigmoidf_(aA);
    float uB = aB * sigmoidf_(aB);
    *(float2*)&u[(size_t)bl * DINNER + c0] = make_float2(uA, uB);
    unsigned hiA = f2bf(uA), loA = f2bf(uA - bf2f(hiA));
    unsigned hiB = f2bf(uB), loB = f2bf(uB - bf2f(hiB));
    *(unsigned*)&ub[(size_t)bl * 1024 + c0] = hiA | (hiB << 16);
    *(unsigned*)&ub[(size_t)bl * 1024 + DINNER + c0] = loA | (loB << 16);
}

// ---------------- delta = softplus(dt @ w_dt + b_dt) from x_dbl ----------------
// block = 256 threads over 8 tokens; w_dt staged in LDS (conflict-free broadcast).
__global__ __launch_bounds__(256) void k_delta(const float* __restrict__ xdbl,
                                               const float* __restrict__ w_dt,
                                               const float* __restrict__ b_dt,
                                               float* __restrict__ delta) {
    const int tid = threadIdx.x;
    const int bl0 = blockIdx.x * 8;
    __shared__ float wdt_s[DTRANK * DINNER];   // 32 KB
    __shared__ float dts[8][DTRANK];
    {
        const float4* wg = (const float4*)w_dt;
        float4* wl = (float4*)wdt_s;
#pragma unroll
        for (int q = 0; q < 8; ++q) wl[tid + q * 256] = wg[tid + q * 256];
    }
    if (tid < 128)
        dts[tid >> 4][tid & 15] = xdbl[(size_t)(bl0 + (tid >> 4)) * XDP + (tid & 15)];
    __syncthreads();
    const int m = tid >> 5;
    const int j = tid & 31;
    float acc[16];
#pragma unroll
    for (int t = 0; t < 16; ++t) acc[t] = b_dt[j + 32 * t];
#pragma unroll
    for (int r = 0; r < DTRANK; ++r) {
        const float dv = dts[m][r];
#pragma unroll
        for (int t = 0; t < 16; ++t)
            acc[t] = fmaf(dv, wdt_s[r * DINNER + j + 32 * t], acc[t]);
    }
#pragma unroll
    for (int t = 0; t < 16; ++t) {
        float s = acc[t];
        delta[(size_t)(bl0 + m) * DINNER + j + 32 * t] = (s > 20.f) ? s : log1pf(__expf(s));
    }
}

// ---------------- chunked selective scan, per-channel 16-state-in-registers ----------------
// B/C read from x_dbl cols 16..31 / 32..47.
__global__ __launch_bounds__(256) void k_scan_a(const float* __restrict__ delta,
                                                const float* __restrict__ u,
                                                const float* __restrict__ xdbl,
                                                const float* __restrict__ A_log,
                                                float* __restrict__ aprod,
                                                float* __restrict__ hend) {
    const int tid = threadIdx.x;
    const int bid = blockIdx.x;
    const int chalf = bid & 1;
    const int k = (bid >> 1) & (NCHUNK - 1);
    const int b = bid >> 7;
    const int c = chalf * 256 + tid;
    const int bl0 = b * LL + k * LC;

    __shared__ float Bs[LC * DSTATE];
    for (int i = tid; i < LC * DSTATE; i += 256)
        Bs[i] = xdbl[(size_t)(bl0 + (i >> 4)) * XDP + 16 + (i & 15)];
    __syncthreads();

    float Ac[DSTATE];
#pragma unroll
    for (int q = 0; q < 4; ++q) {
        float4 a = *(const float4*)&A_log[c * DSTATE + q * 4];
        Ac[q * 4 + 0] = -__expf(a.x); Ac[q * 4 + 1] = -__expf(a.y);
        Ac[q * 4 + 2] = -__expf(a.z); Ac[q * 4 + 3] = -__expf(a.w);
    }

    float h[DSTATE] = {};
    float ap[DSTATE];
#pragma unroll
    for (int n = 0; n < DSTATE; ++n) ap[n] = 1.f;

    float dlt = delta[(size_t)bl0 * DINNER + c];
    float uu  = u[(size_t)bl0 * DINNER + c];
    for (int t = 0; t < LC; ++t) {
        float dlt2 = 0.f, uu2 = 0.f;
        if (t + 1 < LC) {
            dlt2 = delta[(size_t)(bl0 + t + 1) * DINNER + c];
            uu2  = u[(size_t)(bl0 + t + 1) * DINNER + c];
        }
        const float w = dlt * uu;
        const float4* Bs4 = (const float4*)&Bs[t * DSTATE];
        float4 b0 = Bs4[0], b1 = Bs4[1], b2 = Bs4[2], b3 = Bs4[3];
        float bv[DSTATE] = {b0.x, b0.y, b0.z, b0.w, b1.x, b1.y, b1.z, b1.w,
                            b2.x, b2.y, b2.z, b2.w, b3.x, b3.y, b3.z, b3.w};
#pragma unroll
        for (int n = 0; n < DSTATE; ++n) {
            float dA = __expf(dlt * Ac[n]);
            ap[n] *= dA;
            h[n] = fmaf(dA, h[n], w * bv[n]);
        }
        dlt = dlt2; uu = uu2;
    }
    size_t base = ((size_t)(k * BB + b) * DINNER + c) * DSTATE;
#pragma unroll
    for (int q = 0; q < 4; ++q) {
        *(float4*)&aprod[base + q * 4] = make_float4(ap[q*4], ap[q*4+1], ap[q*4+2], ap[q*4+3]);
        *(float4*)&hend[base + q * 4]  = make_float4(h[q*4],  h[q*4+1],  h[q*4+2],  h[q*4+3]);
    }
}

__global__ __launch_bounds__(256) void k_scan_b(const float* __restrict__ aprod,
                                                const float* __restrict__ hend,
                                                float* __restrict__ hstart) {
    int i = blockIdx.x * 256 + threadIdx.x;
    float h = 0.f;
#pragma unroll 4
    for (int k = 0; k < NCHUNK; ++k) {
        size_t idx = (size_t)k * NREC + i;
        float a = aprod[idx];
        float e = hend[idx];
        hstart[idx] = h;
        h = fmaf(a, h, e);
    }
}

// Pass C: re-scan chunk, emit gated output as bf16 hi|lo row-major [BL][2*DINNER]
__global__ __launch_bounds__(256) void k_scan_c(const float* __restrict__ delta,
                                                const float* __restrict__ u,
                                                const float* __restrict__ xz,
                                                const float* __restrict__ xdbl,
                                                const float* __restrict__ A_log,
                                                const float* __restrict__ Dp,
                                                const float* __restrict__ hstart,
                                                ushort* __restrict__ yb) {
    const int tid = threadIdx.x;
    const int bid = blockIdx.x;
    const int chalf = bid & 1;
    const int k = (bid >> 1) & (NCHUNK - 1);
    const int b = bid >> 7;
    const int c = chalf * 256 + tid;
    const int bl0 = b * LL + k * LC;

    __shared__ float Bs[LC * DSTATE];
    __shared__ float Cs[LC * DSTATE];
    for (int i = tid; i < LC * DSTATE; i += 256) {
        Bs[i] = xdbl[(size_t)(bl0 + (i >> 4)) * XDP + 16 + (i & 15)];
        Cs[i] = xdbl[(size_t)(bl0 + (i >> 4)) * XDP + 32 + (i & 15)];
    }
    __syncthreads();

    float Ac[DSTATE];
#pragma unroll
    for (int q = 0; q < 4; ++q) {
        float4 a = *(const float4*)&A_log[c * DSTATE + q * 4];
        Ac[q * 4 + 0] = -__expf(a.x); Ac[q * 4 + 1] = -__expf(a.y);
        Ac[q * 4 + 2] = -__expf(a.z); Ac[q * 4 + 3] = -__expf(a.w);
    }
    const float Dc = Dp[c];

    float h[DSTATE];
    size_t hbase = ((size_t)(k * BB + b) * DINNER + c) * DSTATE;
#pragma unroll
    for (int q = 0; q < 4; ++q) {
        float4 hv = *(const float4*)&hstart[hbase + q * 4];
        h[q*4] = hv.x; h[q*4+1] = hv.y; h[q*4+2] = hv.z; h[q*4+3] = hv.w;
    }

    float dlt = delta[(size_t)bl0 * DINNER + c];
    float uu  = u[(size_t)bl0 * DINNER + c];
    float rr  = xz[(size_t)bl0 * 2 * DINNER + DINNER + c];
    for (int t = 0; t < LC; ++t) {
        float dlt2 = 0.f, uu2 = 0.f, rr2 = 0.f;
        if (t + 1 < LC) {
            dlt2 = delta[(size_t)(bl0 + t + 1) * DINNER + c];
            uu2  = u[(size_t)(bl0 + t + 1) * DINNER + c];
            rr2  = xz[(size_t)(bl0 + t + 1) * 2 * DINNER + DINNER + c];
        }
        const float w = dlt * uu;
        const float4* Bs4 = (const float4*)&Bs[t * DSTATE];
        float4 b0 = Bs4[0], b1 = Bs4[1], b2 = Bs4[2], b3 = Bs4[3];
        float bv[DSTATE] = {b0.x, b0.y, b0.z, b0.w, b1.x, b1.y, b1.z, b1.w,
                            b2.x, b2.y, b2.z, b2.w, b3.x, b3.y, b3.z, b3.w};
        const float4* Cs4 = (const float4*)&Cs[t * DSTATE];
        float4 c0 = Cs4[0], c1 = Cs4[1], c2 = Cs4[2], c3 = Cs4[3];
        float cv[DSTATE] = {c0.x, c0.y, c0.z, c0.w, c1.x, c1.y, c1.z, c1.w,
                            c2.x, c2.y, c2.z, c2.w, c3.x, c3.y, c3.z, c3.w};
        float s0 = 0.f, s1 = 0.f, s2 = 0.f, s3 = 0.f;
#pragma unroll
        for (int n = 0; n < DSTATE; n += 4) {
            float dA0 = __expf(dlt * Ac[n+0]);
            float dA1 = __expf(dlt * Ac[n+1]);
            float dA2 = __expf(dlt * Ac[n+2]);
            float dA3 = __expf(dlt * Ac[n+3]);
            h[n+0] = fmaf(dA0, h[n+0], w * bv[n+0]);
            h[n+1] = fmaf(dA1, h[n+1], w * bv[n+1]);
            h[n+2] = fmaf(dA2, h[n+2], w * bv[n+2]);
            h[n+3] = fmaf(dA3, h[n+3], w * bv[n+3]);
            s0 = fmaf(h[n+0], cv[n+0], s0);
            s1 = fmaf(h[n+1], cv[n+1], s1);
            s2 = fmaf(h[n+2], cv[n+2], s2);
            s3 = fmaf(h[n+3], cv[n+3], s3);
        }
        float yv = (s0 + s1) + (s2 + s3) + uu * Dc;
        float yg = yv * (rr * sigmoidf_(rr));
        unsigned hi = f2bf(yg);
        unsigned lo = f2bf(yg - bf2f(hi));
        yb[(size_t)(bl0 + t) * (2 * DINNER) + c] = (ushort)hi;
        yb[(size_t)(bl0 + t) * (2 * DINNER) + DINNER + c] = (ushort)lo;
        dlt = dlt2; uu = uu2; rr = rr2;
    }
}

extern "C" void kernel_launch(void* const* d_in, const int* in_sizes, int n_in,
                              void* d_out, int out_size, void* d_ws, size_t ws_size,
                              hipStream_t stream) {
    const int*   ids   = (const int*)d_in[0];
    const float* emb   = (const float*)d_in[1];
    const float* w_in  = (const float*)d_in[2];
    const float* cw    = (const float*)d_in[3];
    const float* cb    = (const float*)d_in[4];
    const float* w_xp  = (const float*)d_in[5];
    const float* w_dt  = (const float*)d_in[6];
    const float* b_dt  = (const float*)d_in[7];
    const float* A_log = (const float*)d_in[8];
    const float* Dp    = (const float*)d_in[9];
    const float* w_out = (const float*)d_in[10];
    float* out = (float*)d_out;

    float* ws = (float*)d_ws;
    float* x    = ws;                              // BL*256  (xb bf16 / aprod overlay)
    float* xz   = x  + (size_t)BL * DMODEL;        // BL*1024 (in_proj out + out_proj partials)
    float* u    = xz + (size_t)BL * 2 * DINNER;    // BL*512  fp32 u
    float* dlt  = u  + (size_t)BL * DINNER;        // BL*512  (delta; also xp partials 4x[BL][128])
    float* y    = dlt + (size_t)BL * DINNER;       // BL*512 floats = yb bf16 [BL][1024]
    float* hend = y + (size_t)BL * DINNER;         // NCHUNK*NREC = 2.10M
    float* wfif = hend + (size_t)NCHUNK * NREC;    // 262144 floats (w_in frag)
    float* wfof = wfif + 262144;                   // 131072 floats (w_out frag)
    float* embff = wfof + 131072;                  // 65536 floats (emb bf16 table)
    float* wxff  = embff + 65536;                  // 65536 floats (w_xp frag, padded 128)
    float* xdbl  = wxff + 65536;                   // BL*128 = 1.05M floats
    float* ubf   = xdbl + (size_t)BL * XDP;        // BL*1024 ushorts = 4.19M floats
    float* aprod  = x;
    float* hstart = aprod;
    ushort* xb   = (ushort*)x;      // [BL][512] hi|lo, written by red4<true> (layer 0)
    ushort* yb   = (ushort*)y;      // [BL][1024] hi|lo, written by scan_c
    ushort* wfi  = (ushort*)wfif;
    ushort* wfo  = (ushort*)wfof;
    ushort* embf = (ushort*)embff;  // [VOCAB][512] hi|lo
    ushort* wxf  = (ushort*)wxff;   // [8][32][512]
    ushort* ub   = (ushort*)ubf;    // [BL][1024] hi|lo u

    k_cvt_emb<<<VOCAB, DMODEL, 0, stream>>>(emb, embf);

    for (int l = 0; l < NLAYER; ++l) {
        // ---- in_proj: xz = A @ w_in via split-bf16 MFMA (row-major A, per-lane gather)
        k_cvt_w<DMODEL><<<128, 256, 0, stream>>>(w_in + (size_t)l * DMODEL * 2 * DINNER,
                                                 wfi, 2 * DINNER);
        if (l == 0)
            k_mgemm<1, true><<<dim3(2 * DINNER / 128, BL / 128, 1), 256, 0, stream>>>(
                embf, wfi, xz, BL, 2 * DINNER, 2 * DMODEL, ids);
        else
            k_mgemm<1, false><<<dim3(2 * DINNER / 128, BL / 128, 1), 256, 0, stream>>>(
                xb, wfi, xz, BL, 2 * DINNER, 2 * DMODEL, ids);

        // ---- conv + SiLU -> u fp32 + ub bf16
        k_conv<<<BL, 256, 0, stream>>>(xz, cw + l * DINNER * DCONV, cb + l * DINNER, u, ub);

        // ---- x_proj: x_dbl = ub @ w_xp (padded 48->128), split-K=4, partials in dlt
        k_cvt_wxp<DINNER><<<32, 256, 0, stream>>>(w_xp + (size_t)l * DINNER * 48, wxf);
        k_mgemm<4, false><<<dim3(1, BL / 128, 4), 256, 0, stream>>>(
            ub, wxf, dlt, BL, XDP, 2 * DINNER, ids);
        k_red4<false><<<(BL * XDP / 4) / 256, 256, 0, stream>>>(dlt, xdbl, nullptr,
                                                               BL * XDP / 4);

        // ---- delta = softplus(dt @ w_dt + b_dt)
        k_delta<<<BL / 8, 256, 0, stream>>>(xdbl, w_dt + (size_t)l * DTRANK * DINNER,
                                            b_dt + (size_t)l * DINNER, dlt);

        const float* Al = A_log + (size_t)l * DINNER * DSTATE;
        k_scan_a<<<BB * NCHUNK * 2, 256, 0, stream>>>(dlt, u, xdbl, Al, aprod, hend);
        k_scan_b<<<NREC / 256, 256, 0, stream>>>(aprod, hend, hstart);
        k_scan_c<<<BB * NCHUNK * 2, 256, 0, stream>>>(dlt, u, xz, xdbl, Al,
                                                      Dp + (size_t)l * DINNER, hstart, yb);

        // ---- out_proj: dst = y @ w_out via split-bf16 MFMA, split-K=4 into xz
        k_cvt_w<DINNER><<<64, 256, 0, stream>>>(w_out + (size_t)l * DINNER * DMODEL,
                                                wfo, DMODEL);
        k_mgemm<4, false><<<dim3(DMODEL / 128, BL / 128, 4), 256, 0, stream>>>(
            yb, wfo, xz, BL, DMODEL, 2 * DINNER, ids);
        if (l == NLAYER - 1)
            k_red4<false><<<(BL * DMODEL / 4) / 256, 256, 0, stream>>>(xz, out, xb,
                                                                       BL * DMODEL / 4);
        else
            k_red4<true><<<(BL * DMODEL / 4) / 256, 256, 0, stream>>>(xz, out, xb,
                                                                      BL * DMODEL / 4);
    }
}

// Round 14
// 302.716 us; speedup vs baseline: 1.2059x; 1.2059x over previous
//
#include <hip/hip_runtime.h>
#include <math.h>

#define NLAYER 2
#define DMODEL 256
#define DINNER 512
#define DSTATE 16
#define DTRANK 16
#define DCONV  4
#define BB     4
#define LL     2048
#define BL     (BB*LL)
#define NCHUNK 64
#define LC     (LL/NCHUNK)          // 32
#define NREC   (BB*DINNER*DSTATE)   // 32768
#define VOCAB  256

typedef __attribute__((ext_vector_type(8))) short short8;   // 8 bf16 (4 VGPRs)
typedef __attribute__((ext_vector_type(4))) float f32x4;    // 4 fp32 acc

__device__ __forceinline__ float sigmoidf_(float x) { return 1.0f / (1.0f + __expf(-x)); }

// fp32 -> bf16 round-to-nearest-even (bit pattern) and back
__device__ __forceinline__ unsigned f2bf(float a) {
    unsigned u = __builtin_bit_cast(unsigned, a);
    return (u + 0x7fffu + ((u >> 16) & 1u)) >> 16;
}
__device__ __forceinline__ float bf2f(unsigned h) {
    return __builtin_bit_cast(float, h << 16);
}

// ---------------- embedding -> bf16 hi|lo table [VOCAB][2*DMODEL] ----------------
__global__ __launch_bounds__(256) void k_cvt_emb(const float* __restrict__ emb,
                                                 ushort* __restrict__ embf) {
    const int v = blockIdx.x;
    const int c = threadIdx.x;
    float s = emb[(size_t)v * DMODEL + c];
    unsigned hi = f2bf(s);
    unsigned lo = f2bf(s - bf2f(hi));
    embf[(size_t)v * (2 * DMODEL) + c] = (ushort)hi;
    embf[(size_t)v * (2 * DMODEL) + DMODEL + c] = (ushort)lo;
}

// ---------------- weight fp32 [K,N] -> frag bf16 hi/lo ----------------
// frag layout: [N/16][2K/32][64][8]; lane l holds B[kf*32+(l>>4)*8+j][nf*16+(l&15)]
template<int K>
__global__ __launch_bounds__(256) void k_cvt_w(const float* __restrict__ W,
                                               ushort* __restrict__ F, int N) {
    constexpr int NKF = K / 32;
    const int t = blockIdx.x * 256 + threadIdx.x;
    const int l = t & 63;
    const int cid = t >> 6;
    const int kf = cid % NKF;
    const int nf = cid / NKF;
    const int col = nf * 16 + (l & 15);
    const int k0 = kf * 32 + (l >> 4) * 8;
    float s[8];
#pragma unroll
    for (int j = 0; j < 8; ++j) s[j] = W[(size_t)(k0 + j) * N + col];
    unsigned hi[8], lo[8];
#pragma unroll
    for (int j = 0; j < 8; ++j) {
        hi[j] = f2bf(s[j]);
        lo[j] = f2bf(s[j] - bf2f(hi[j]));
    }
    uint4 ph = make_uint4(hi[0] | (hi[1] << 16), hi[2] | (hi[3] << 16),
                          hi[4] | (hi[5] << 16), hi[6] | (hi[7] << 16));
    uint4 pl = make_uint4(lo[0] | (lo[1] << 16), lo[2] | (lo[3] << 16),
                          lo[4] | (lo[5] << 16), lo[6] | (lo[7] << 16));
    size_t ohi = ((size_t)nf * (2 * NKF) + kf) * 512 + l * 8;
    *(uint4*)&F[ohi] = ph;
    *(uint4*)&F[ohi + (size_t)NKF * 512] = pl;
}

// ---------------- bf16 MFMA GEMM: A row-major bf16 [M][KE] (per-lane gather), B frag ----------------
template<int SPLITK, bool IDS>
__global__ __launch_bounds__(256) void k_mgemm(const ushort* __restrict__ A,
                                               const ushort* __restrict__ Bf,
                                               float* __restrict__ C,
                                               int M, int N, int KE,
                                               const int* __restrict__ ids) {
    __shared__ __align__(16) ushort As[8 * 512];
    __shared__ __align__(16) ushort Bs[8 * 512];
    const int tid = threadIdx.x;
    const int w = tid >> 6, lane = tid & 63;
    const int n0 = blockIdx.x * 128, m0 = blockIdx.y * 128;
    const int nkf = KE >> 5;
    const int KT = nkf / SPLITK;
    const int kt0 = blockIdx.z * KT;
    const int wm = w & 1, wn = w >> 1;
    const int c0 = 2 * w, c1 = c0 + 1;

    f32x4 acc[4][4] = {};

    int row0 = m0 + c0 * 16 + (lane & 15);
    int row1 = m0 + c1 * 16 + (lane & 15);
    if (IDS) { row0 = ids[row0]; row1 = ids[row1]; }
    const ushort* Ap0 = A + (size_t)row0 * KE + (lane >> 4) * 8;
    const ushort* Ap1 = A + (size_t)row1 * KE + (lane >> 4) * 8;
    const ushort* Bb0 = Bf + ((size_t)(n0 / 16 + c0) * nkf) * 512 + lane * 8;
    const ushort* Bb1 = Bf + ((size_t)(n0 / 16 + c1) * nkf) * 512 + lane * 8;
    ushort* As0 = As + c0 * 512 + lane * 8;
    ushort* As1 = As + c1 * 512 + lane * 8;
    ushort* Bs0 = Bs + c0 * 512 + lane * 8;
    ushort* Bs1 = Bs + c1 * 512 + lane * 8;

    for (int kt = kt0; kt < kt0 + KT; ++kt) {
        __builtin_amdgcn_global_load_lds((const __attribute__((address_space(1))) void*)(Ap0 + kt * 32),
                                         (__attribute__((address_space(3))) void*)As0, 16, 0, 0);
        __builtin_amdgcn_global_load_lds((const __attribute__((address_space(1))) void*)(Ap1 + kt * 32),
                                         (__attribute__((address_space(3))) void*)As1, 16, 0, 0);
        __builtin_amdgcn_global_load_lds((const __attribute__((address_space(1))) void*)(Bb0 + (size_t)kt * 512),
                                         (__attribute__((address_space(3))) void*)Bs0, 16, 0, 0);
        __builtin_amdgcn_global_load_lds((const __attribute__((address_space(1))) void*)(Bb1 + (size_t)kt * 512),
                                         (__attribute__((address_space(3))) void*)Bs1, 16, 0, 0);
        __syncthreads();
        short8 av[4], bv[4];
#pragma unroll
        for (int i = 0; i < 4; ++i)
            av[i] = *(const short8*)&As[(wm * 4 + i) * 512 + lane * 8];
#pragma unroll
        for (int i = 0; i < 4; ++i)
            bv[i] = *(const short8*)&Bs[(wn * 4 + i) * 512 + lane * 8];
#pragma unroll
        for (int mi = 0; mi < 4; ++mi)
#pragma unroll
            for (int ni = 0; ni < 4; ++ni)
                acc[mi][ni] = __builtin_amdgcn_mfma_f32_16x16x32_bf16(av[mi], bv[ni],
                                                                      acc[mi][ni], 0, 0, 0);
        __syncthreads();
    }

    // C/D layout (m89-verified): col = lane&15, row = (lane>>4)*4 + reg
    float* Cw = C + (size_t)blockIdx.z * ((size_t)M * N);
    const int r0 = (lane >> 4) * 4, cc = lane & 15;
#pragma unroll
    for (int mi = 0; mi < 4; ++mi)
#pragma unroll
        for (int r = 0; r < 4; ++r) {
            const int row = m0 + wm * 64 + mi * 16 + r0 + r;
            float* crow = &Cw[(size_t)row * N + n0 + wn * 64 + cc];
#pragma unroll
            for (int ni = 0; ni < 4; ++ni) crow[ni * 16] = acc[mi][ni][r];
        }
}

// sum 4 M*N slabs; TOBF: write bf16 hi|lo row-major [BL][2*DMODEL] instead of fp32
template<bool TOBF>
__global__ __launch_bounds__(256) void k_red4(const float* __restrict__ p,
                                              float* __restrict__ o,
                                              ushort* __restrict__ xb, int n4) {
    int i = blockIdx.x * 256 + threadIdx.x;
    const float4* p4 = (const float4*)p;
    float4 a = p4[i], b = p4[i + n4], c = p4[i + 2 * n4], d = p4[i + 3 * n4];
    float4 r = make_float4(a.x + b.x + c.x + d.x, a.y + b.y + c.y + d.y,
                           a.z + b.z + c.z + d.z, a.w + b.w + c.w + d.w);
    if (TOBF) {
        const int e0 = i * 4;
        const int bl = e0 >> 8;
        const int cl = e0 & 255;
        float s[4] = {r.x, r.y, r.z, r.w};
        unsigned hi[4], lo[4];
#pragma unroll
        for (int j = 0; j < 4; ++j) {
            hi[j] = f2bf(s[j]);
            lo[j] = f2bf(s[j] - bf2f(hi[j]));
        }
        *(uint2*)&xb[(size_t)bl * 512 + cl] =
            make_uint2(hi[0] | (hi[1] << 16), hi[2] | (hi[3] << 16));
        *(uint2*)&xb[(size_t)bl * 512 + 256 + cl] =
            make_uint2(lo[0] | (lo[1] << 16), lo[2] | (lo[3] << 16));
    } else {
        ((float4*)o)[i] = r;
    }
}

// ---------------- fused conv+SiLU + x_proj + delta (16 tokens/block, 512 blocks) ----------------
// Phase 0: depthwise causal conv + bias + SiLU -> us packed bf16 hi|lo (LDS) + u (global).
// Phase 1: x_proj with LDS-staged w_xp (stride 48, measured conflict-free),
//          register-double-buffered chunk staging, 2-token register reuse.
// Phase 2: delta = softplus(dt @ w_dt + b_dt).
// LDS: 16 KB us_p + 24 KB wsx + 1 KB dts = 41 KB -> 3 blocks/CU.
__global__ __launch_bounds__(256) void k_xpd(const float* __restrict__ xz,
                                             const float* __restrict__ cw,
                                             const float* __restrict__ cb,
                                             const float* __restrict__ w_xp,
                                             const float* __restrict__ w_dt,
                                             const float* __restrict__ b_dt,
                                             float* __restrict__ u,
                                             float* __restrict__ Bm,
                                             float* __restrict__ Cm,
                                             float* __restrict__ delta) {
    const int tid = threadIdx.x;
    const int bl0 = blockIdx.x * 16;
    __shared__ unsigned us_p[16 * DINNER];  // 16 KB: u as bf16 hi|lo packed in uint
    __shared__ float wsx[128 * 48];         // 24 KB (one chunk of w_xp)
    __shared__ float dts[16][DTRANK];       // 1 KB

    // ---- phase 0: conv + SiLU for 16 tokens (each thread: channels tid, tid+256)
    {
        const int ch0 = tid, ch1 = 256 + tid;
        float4 cwA = *(const float4*)&cw[ch0 * 4];
        float4 cwB = *(const float4*)&cw[ch1 * 4];
        const float cbA = cb[ch0], cbB = cb[ch1];
        const int lbase = bl0 & (LL - 1);
#pragma unroll
        for (int m = 0; m < 16; ++m) {
            const int bl = bl0 + m;
            const int lpos = lbase + m;
            float aA = cbA, aB = cbB;
#pragma unroll
            for (int k = 0; k < DCONV; ++k) {
                int tt = lpos - (DCONV - 1) + k;
                if (tt >= 0) {
                    const float* xr = &xz[(size_t)(bl - (DCONV - 1) + k) * 2 * DINNER];
                    aA = fmaf(((const float*)&cwA)[k], xr[ch0], aA);
                    aB = fmaf(((const float*)&cwB)[k], xr[ch1], aB);
                }
            }
            float uA = aA * sigmoidf_(aA);
            float uB = aB * sigmoidf_(aB);
            unsigned hA = f2bf(uA), lA = f2bf(uA - bf2f(hA));
            unsigned hB = f2bf(uB), lB = f2bf(uB - bf2f(hB));
            us_p[m * DINNER + ch0] = hA | (lA << 16);
            us_p[m * DINNER + ch1] = hB | (lB << 16);
            u[(size_t)bl * DINNER + ch0] = uA;
            u[(size_t)bl * DINNER + ch1] = uB;
        }
    }

    const int mp = tid >> 5;
    const int jg = (tid >> 3) & 3;
    const int s  = tid & 7;
    const unsigned* usm0 = &us_p[(mp * 2 + 0) * DINNER];
    const unsigned* usm1 = &us_p[(mp * 2 + 1) * DINNER];

    float acc0[12] = {}, acc1[12] = {};
    // register prefetch of w_xp chunk 0
    float4 wreg[6];
#pragma unroll
    for (int q = 0; q < 6; ++q)
        wreg[q] = ((const float4*)w_xp)[tid + q * 256];

#pragma unroll 1
    for (int ck = 0; ck < 4; ++ck) {
        __syncthreads();   // us ready (ck=0); wsx consumers done (ck>0)
        {
            float4* wl = (float4*)wsx;
#pragma unroll
            for (int q = 0; q < 6; ++q) wl[tid + q * 256] = wreg[q];
        }
        if (ck < 3) {      // issue next chunk loads; complete under compute
            const float4* wg = (const float4*)&w_xp[(ck + 1) * 128 * 48];
#pragma unroll
            for (int q = 0; q < 6; ++q) wreg[q] = wg[tid + q * 256];
        }
        __syncthreads();
#pragma unroll
        for (int i = 0; i < 16; ++i) {
            const int kl = i * 8 + s;
            unsigned p0 = usm0[ck * 128 + kl];
            unsigned p1 = usm1[ck * 128 + kl];
            const float a0 = bf2f(p0 & 0xffffu) + bf2f(p0 >> 16);
            const float a1 = bf2f(p1 & 0xffffu) + bf2f(p1 >> 16);
            const float* wr = &wsx[kl * 48 + jg * 12];
            float4 w0 = *(const float4*)&wr[0];
            float4 w1 = *(const float4*)&wr[4];
            float4 w2 = *(const float4*)&wr[8];
            acc0[0]  = fmaf(a0, w0.x, acc0[0]);  acc1[0]  = fmaf(a1, w0.x, acc1[0]);
            acc0[1]  = fmaf(a0, w0.y, acc0[1]);  acc1[1]  = fmaf(a1, w0.y, acc1[1]);
            acc0[2]  = fmaf(a0, w0.z, acc0[2]);  acc1[2]  = fmaf(a1, w0.z, acc1[2]);
            acc0[3]  = fmaf(a0, w0.w, acc0[3]);  acc1[3]  = fmaf(a1, w0.w, acc1[3]);
            acc0[4]  = fmaf(a0, w1.x, acc0[4]);  acc1[4]  = fmaf(a1, w1.x, acc1[4]);
            acc0[5]  = fmaf(a0, w1.y, acc0[5]);  acc1[5]  = fmaf(a1, w1.y, acc1[5]);
            acc0[6]  = fmaf(a0, w1.z, acc0[6]);  acc1[6]  = fmaf(a1, w1.z, acc1[6]);
            acc0[7]  = fmaf(a0, w1.w, acc0[7]);  acc1[7]  = fmaf(a1, w1.w, acc1[7]);
            acc0[8]  = fmaf(a0, w2.x, acc0[8]);  acc1[8]  = fmaf(a1, w2.x, acc1[8]);
            acc0[9]  = fmaf(a0, w2.y, acc0[9]);  acc1[9]  = fmaf(a1, w2.y, acc1[9]);
            acc0[10] = fmaf(a0, w2.z, acc0[10]); acc1[10] = fmaf(a1, w2.z, acc1[10]);
            acc0[11] = fmaf(a0, w2.w, acc0[11]); acc1[11] = fmaf(a1, w2.w, acc1[11]);
        }
    }
    // butterfly reduce across the 8 k-slice lanes
#pragma unroll
    for (int off = 4; off >= 1; off >>= 1) {
#pragma unroll
        for (int j = 0; j < 12; ++j) {
            acc0[j] += __shfl_xor(acc0[j], off, 8);
            acc1[j] += __shfl_xor(acc1[j], off, 8);
        }
    }
    if (s < 6) {
        const int bl_a = bl0 + mp * 2 + 0;
        const int bl_b = bl0 + mp * 2 + 1;
#pragma unroll
        for (int q = 0; q < 2; ++q) {
            int j = jg * 12 + s * 2 + q;
            float v0 = acc0[s * 2 + q];
            float v1 = acc1[s * 2 + q];
            if (j < 16) {
                dts[mp * 2 + 0][j] = v0;
                dts[mp * 2 + 1][j] = v1;
            } else if (j < 32) {
                Bm[(size_t)bl_a * DSTATE + (j - 16)] = v0;
                Bm[(size_t)bl_b * DSTATE + (j - 16)] = v1;
            } else {
                Cm[(size_t)bl_a * DSTATE + (j - 32)] = v0;
                Cm[(size_t)bl_b * DSTATE + (j - 32)] = v1;
            }
        }
    }
    __syncthreads();

    // phase 2: delta = softplus(dt @ w_dt + b_dt); thread: 4 channels x 8 tokens
    const int c0 = (tid & 127) * 4;
    const int mb = (tid >> 7) * 8;
    float4 bd = *(const float4*)&b_dt[c0];
    float a0[8], a1[8], a2[8], a3[8];
#pragma unroll
    for (int t = 0; t < 8; ++t) { a0[t] = bd.x; a1[t] = bd.y; a2[t] = bd.z; a3[t] = bd.w; }
#pragma unroll
    for (int r = 0; r < DTRANK; ++r) {
        float4 w4 = *(const float4*)&w_dt[r * DINNER + c0];
#pragma unroll
        for (int t = 0; t < 8; ++t) {
            float f = dts[mb + t][r];
            a0[t] = fmaf(f, w4.x, a0[t]);
            a1[t] = fmaf(f, w4.y, a1[t]);
            a2[t] = fmaf(f, w4.z, a2[t]);
            a3[t] = fmaf(f, w4.w, a3[t]);
        }
    }
#pragma unroll
    for (int t = 0; t < 8; ++t) {
        float4 o;
        o.x = (a0[t] > 20.f) ? a0[t] : log1pf(__expf(a0[t]));
        o.y = (a1[t] > 20.f) ? a1[t] : log1pf(__expf(a1[t]));
        o.z = (a2[t] > 20.f) ? a2[t] : log1pf(__expf(a2[t]));
        o.w = (a3[t] > 20.f) ? a3[t] : log1pf(__expf(a3[t]));
        *(float4*)&delta[(size_t)(bl0 + mb + t) * DINNER + c0] = o;
    }
}

// ---------------- chunked selective scan, per-channel 16-state-in-registers ----------------
__global__ __launch_bounds__(256) void k_scan_a(const float* __restrict__ delta,
                                                const float* __restrict__ u,
                                                const float* __restrict__ Bm,
                                                const float* __restrict__ A_log,
                                                float* __restrict__ aprod,
                                                float* __restrict__ hend) {
    const int tid = threadIdx.x;
    const int bid = blockIdx.x;
    const int chalf = bid & 1;
    const int k = (bid >> 1) & (NCHUNK - 1);
    const int b = bid >> 7;
    const int c = chalf * 256 + tid;
    const int bl0 = b * LL + k * LC;

    __shared__ float Bs[LC * DSTATE];
    for (int i = tid; i < LC * DSTATE; i += 256) Bs[i] = Bm[(size_t)bl0 * DSTATE + i];
    __syncthreads();

    float Ac[DSTATE];
#pragma unroll
    for (int q = 0; q < 4; ++q) {
        float4 a = *(const float4*)&A_log[c * DSTATE + q * 4];
        Ac[q * 4 + 0] = -__expf(a.x); Ac[q * 4 + 1] = -__expf(a.y);
        Ac[q * 4 + 2] = -__expf(a.z); Ac[q * 4 + 3] = -__expf(a.w);
    }

    float h[DSTATE] = {};
    float ap[DSTATE];
#pragma unroll
    for (int n = 0; n < DSTATE; ++n) ap[n] = 1.f;

    float dlt = delta[(size_t)bl0 * DINNER + c];
    float uu  = u[(size_t)bl0 * DINNER + c];
    for (int t = 0; t < LC; ++t) {
        float dlt2 = 0.f, uu2 = 0.f;
        if (t + 1 < LC) {
            dlt2 = delta[(size_t)(bl0 + t + 1) * DINNER + c];
            uu2  = u[(size_t)(bl0 + t + 1) * DINNER + c];
        }
        const float w = dlt * uu;
        const float4* Bs4 = (const float4*)&Bs[t * DSTATE];
        float4 b0 = Bs4[0], b1 = Bs4[1], b2 = Bs4[2], b3 = Bs4[3];
        float bv[DSTATE] = {b0.x, b0.y, b0.z, b0.w, b1.x, b1.y, b1.z, b1.w,
                            b2.x, b2.y, b2.z, b2.w, b3.x, b3.y, b3.z, b3.w};
#pragma unroll
        for (int n = 0; n < DSTATE; ++n) {
            float dA = __expf(dlt * Ac[n]);
            ap[n] *= dA;
            h[n] = fmaf(dA, h[n], w * bv[n]);
        }
        dlt = dlt2; uu = uu2;
    }
    size_t base = ((size_t)(k * BB + b) * DINNER + c) * DSTATE;
#pragma unroll
    for (int q = 0; q < 4; ++q) {
        *(float4*)&aprod[base + q * 4] = make_float4(ap[q*4], ap[q*4+1], ap[q*4+2], ap[q*4+3]);
        *(float4*)&hend[base + q * 4]  = make_float4(h[q*4],  h[q*4+1],  h[q*4+2],  h[q*4+3]);
    }
}

__global__ __launch_bounds__(256) void k_scan_b(const float* __restrict__ aprod,
                                                const float* __restrict__ hend,
                                                float* __restrict__ hstart) {
    int i = blockIdx.x * 256 + threadIdx.x;
    float h = 0.f;
#pragma unroll 4
    for (int k = 0; k < NCHUNK; ++k) {
        size_t idx = (size_t)k * NREC + i;
        float a = aprod[idx];
        float e = hend[idx];
        hstart[idx] = h;
        h = fmaf(a, h, e);
    }
}

// Pass C: re-scan chunk, emit gated output as bf16 hi|lo row-major [BL][2*DINNER]
__global__ __launch_bounds__(256) void k_scan_c(const float* __restrict__ delta,
                                                const float* __restrict__ u,
                                                const float* __restrict__ xz,
                                                const float* __restrict__ Bm,
                                                const float* __restrict__ Cm,
                                                const float* __restrict__ A_log,
                                                const float* __restrict__ Dp,
                                                const float* __restrict__ hstart,
                                                ushort* __restrict__ yb) {
    const int tid = threadIdx.x;
    const int bid = blockIdx.x;
    const int chalf = bid & 1;
    const int k = (bid >> 1) & (NCHUNK - 1);
    const int b = bid >> 7;
    const int c = chalf * 256 + tid;
    const int bl0 = b * LL + k * LC;

    __shared__ float Bs[LC * DSTATE];
    __shared__ float Cs[LC * DSTATE];
    for (int i = tid; i < LC * DSTATE; i += 256) {
        Bs[i] = Bm[(size_t)bl0 * DSTATE + i];
        Cs[i] = Cm[(size_t)bl0 * DSTATE + i];
    }
    __syncthreads();

    float Ac[DSTATE];
#pragma unroll
    for (int q = 0; q < 4; ++q) {
        float4 a = *(const float4*)&A_log[c * DSTATE + q * 4];
        Ac[q * 4 + 0] = -__expf(a.x); Ac[q * 4 + 1] = -__expf(a.y);
        Ac[q * 4 + 2] = -__expf(a.z); Ac[q * 4 + 3] = -__expf(a.w);
    }
    const float Dc = Dp[c];

    float h[DSTATE];
    size_t hbase = ((size_t)(k * BB + b) * DINNER + c) * DSTATE;
#pragma unroll
    for (int q = 0; q < 4; ++q) {
        float4 hv = *(const float4*)&hstart[hbase + q * 4];
        h[q*4] = hv.x; h[q*4+1] = hv.y; h[q*4+2] = hv.z; h[q*4+3] = hv.w;
    }

    float dlt = delta[(size_t)bl0 * DINNER + c];
    float uu  = u[(size_t)bl0 * DINNER + c];
    float rr  = xz[(size_t)bl0 * 2 * DINNER + DINNER + c];
    for (int t = 0; t < LC; ++t) {
        float dlt2 = 0.f, uu2 = 0.f, rr2 = 0.f;
        if (t + 1 < LC) {
            dlt2 = delta[(size_t)(bl0 + t + 1) * DINNER + c];
            uu2  = u[(size_t)(bl0 + t + 1) * DINNER + c];
            rr2  = xz[(size_t)(bl0 + t + 1) * 2 * DINNER + DINNER + c];
        }
        const float w = dlt * uu;
        const float4* Bs4 = (const float4*)&Bs[t * DSTATE];
        float4 b0 = Bs4[0], b1 = Bs4[1], b2 = Bs4[2], b3 = Bs4[3];
        float bv[DSTATE] = {b0.x, b0.y, b0.z, b0.w, b1.x, b1.y, b1.z, b1.w,
                            b2.x, b2.y, b2.z, b2.w, b3.x, b3.y, b3.z, b3.w};
        const float4* Cs4 = (const float4*)&Cs[t * DSTATE];
        float4 c0 = Cs4[0], c1 = Cs4[1], c2 = Cs4[2], c3 = Cs4[3];
        float cv[DSTATE] = {c0.x, c0.y, c0.z, c0.w, c1.x, c1.y, c1.z, c1.w,
                            c2.x, c2.y, c2.z, c2.w, c3.x, c3.y, c3.z, c3.w};
        float s0 = 0.f, s1 = 0.f, s2 = 0.f, s3 = 0.f;
#pragma unroll
        for (int n = 0; n < DSTATE; n += 4) {
            float dA0 = __expf(dlt * Ac[n+0]);
            float dA1 = __expf(dlt * Ac[n+1]);
            float dA2 = __expf(dlt * Ac[n+2]);
            float dA3 = __expf(dlt * Ac[n+3]);
            h[n+0] = fmaf(dA0, h[n+0], w * bv[n+0]);
            h[n+1] = fmaf(dA1, h[n+1], w * bv[n+1]);
            h[n+2] = fmaf(dA2, h[n+2], w * bv[n+2]);
            h[n+3] = fmaf(dA3, h[n+3], w * bv[n+3]);
            s0 = fmaf(h[n+0], cv[n+0], s0);
            s1 = fmaf(h[n+1], cv[n+1], s1);
            s2 = fmaf(h[n+2], cv[n+2], s2);
            s3 = fmaf(h[n+3], cv[n+3], s3);
        }
        float yv = (s0 + s1) + (s2 + s3) + uu * Dc;
        float yg = yv * (rr * sigmoidf_(rr));
        unsigned hi = f2bf(yg);
        unsigned lo = f2bf(yg - bf2f(hi));
        yb[(size_t)(bl0 + t) * (2 * DINNER) + c] = (ushort)hi;
        yb[(size_t)(bl0 + t) * (2 * DINNER) + DINNER + c] = (ushort)lo;
        dlt = dlt2; uu = uu2; rr = rr2;
    }
}

extern "C" void kernel_launch(void* const* d_in, const int* in_sizes, int n_in,
                              void* d_out, int out_size, void* d_ws, size_t ws_size,
                              hipStream_t stream) {
    const int*   ids   = (const int*)d_in[0];
    const float* emb   = (const float*)d_in[1];
    const float* w_in  = (const float*)d_in[2];
    const float* cw    = (const float*)d_in[3];
    const float* cb    = (const float*)d_in[4];
    const float* w_xp  = (const float*)d_in[5];
    const float* w_dt  = (const float*)d_in[6];
    const float* b_dt  = (const float*)d_in[7];
    const float* A_log = (const float*)d_in[8];
    const float* Dp    = (const float*)d_in[9];
    const float* w_out = (const float*)d_in[10];
    float* out = (float*)d_out;

    float* ws = (float*)d_ws;
    float* x    = ws;                              // BL*256  floats (xb bf16 / aprod overlay)
    float* xz   = x  + (size_t)BL * DMODEL;        // BL*1024 (also split-K partials)
    float* u    = xz + (size_t)BL * 2 * DINNER;    // BL*512
    float* Bm   = u  + (size_t)BL * DINNER;        // BL*16
    float* Cm   = Bm + (size_t)BL * DSTATE;        // BL*16
    float* dlt  = Cm + (size_t)BL * DSTATE;        // BL*512
    float* y    = dlt + (size_t)BL * DINNER;       // BL*512 floats = yb bf16 [BL][1024]
    float* hend = y + (size_t)BL * DINNER;         // NCHUNK*NREC = 2.10M
    float* wfif = hend + (size_t)NCHUNK * NREC;    // 262144 floats (w_in frag)
    float* wfof = wfif + 262144;                   // 131072 floats (w_out frag)
    float* embff = wfof + 131072;                  // 65536 floats (emb bf16 table)
    float* aprod  = x;
    float* hstart = aprod;
    ushort* xb   = (ushort*)x;      // [BL][512] hi|lo, written by red4<true> (layer 0)
    ushort* yb   = (ushort*)y;      // [BL][1024] hi|lo, written by scan_c
    ushort* wfi  = (ushort*)wfif;
    ushort* wfo  = (ushort*)wfof;
    ushort* embf = (ushort*)embff;  // [VOCAB][512] hi|lo

    k_cvt_emb<<<VOCAB, DMODEL, 0, stream>>>(emb, embf);

    for (int l = 0; l < NLAYER; ++l) {
        // ---- in_proj: xz = A @ w_in via split-bf16 MFMA (row-major A, per-lane gather)
        k_cvt_w<DMODEL><<<128, 256, 0, stream>>>(w_in + (size_t)l * DMODEL * 2 * DINNER,
                                                 wfi, 2 * DINNER);
        if (l == 0)
            k_mgemm<1, true><<<dim3(2 * DINNER / 128, BL / 128, 1), 256, 0, stream>>>(
                embf, wfi, xz, BL, 2 * DINNER, 2 * DMODEL, ids);
        else
            k_mgemm<1, false><<<dim3(2 * DINNER / 128, BL / 128, 1), 256, 0, stream>>>(
                xb, wfi, xz, BL, 2 * DINNER, 2 * DMODEL, ids);

        // ---- fused conv+silu + x_proj + delta
        k_xpd<<<BL / 16, 256, 0, stream>>>(xz, cw + l * DINNER * DCONV, cb + l * DINNER,
                                           w_xp + (size_t)l * DINNER * 48,
                                           w_dt + (size_t)l * DTRANK * DINNER,
                                           b_dt + (size_t)l * DINNER, u, Bm, Cm, dlt);

        const float* Al = A_log + (size_t)l * DINNER * DSTATE;
        k_scan_a<<<BB * NCHUNK * 2, 256, 0, stream>>>(dlt, u, Bm, Al, aprod, hend);
        k_scan_b<<<NREC / 256, 256, 0, stream>>>(aprod, hend, hstart);
        k_scan_c<<<BB * NCHUNK * 2, 256, 0, stream>>>(dlt, u, xz, Bm, Cm, Al,
                                                      Dp + (size_t)l * DINNER, hstart, yb);

        // ---- out_proj: dst = y @ w_out via split-bf16 MFMA, split-K=4 into xz
        k_cvt_w<DINNER><<<64, 256, 0, stream>>>(w_out + (size_t)l * DINNER * DMODEL,
                                                wfo, DMODEL);
        k_mgemm<4, false><<<dim3(DMODEL / 128, BL / 128, 4), 256, 0, stream>>>(
            yb, wfo, xz, BL, DMODEL, 2 * DINNER, ids);
        if (l == NLAYER - 1)
            k_red4<false><<<(BL * DMODEL / 4) / 256, 256, 0, stream>>>(xz, out, xb,
                                                                       BL * DMODEL / 4);
        else
            k_red4<true><<<(BL * DMODEL / 4) / 256, 256, 0, stream>>>(xz, out, xb,
                                                                      BL * DMODEL / 4);
    }
}

// Round 17
// 288.837 us; speedup vs baseline: 1.2638x; 1.0481x over previous
//
#include <hip/hip_runtime.h>
#include <math.h>

#define NLAYER 2
#define DMODEL 256
#define DINNER 512
#define DSTATE 16
#define DTRANK 16
#define DCONV  4
#define BB     4
#define LL     2048
#define BL     (BB*LL)
#define NCHUNK 64
#define LC     (LL/NCHUNK)          // 32
#define NREC   (BB*DINNER*DSTATE)   // 32768
#define VOCAB  256

typedef __attribute__((ext_vector_type(8))) short short8;   // 8 bf16 (4 VGPRs)
typedef __attribute__((ext_vector_type(4))) float f32x4;    // 4 fp32 acc

__device__ __forceinline__ float sigmoidf_(float x) { return 1.0f / (1.0f + __expf(-x)); }

// fp32 -> bf16 round-to-nearest-even (bit pattern) and back
__device__ __forceinline__ unsigned f2bf(float a) {
    unsigned u = __builtin_bit_cast(unsigned, a);
    return (u + 0x7fffu + ((u >> 16) & 1u)) >> 16;
}
__device__ __forceinline__ float bf2f(unsigned h) {
    return __builtin_bit_cast(float, h << 16);
}

// ---------------- embedding -> bf16 hi|lo table [VOCAB][2*DMODEL] ----------------
__global__ __launch_bounds__(256) void k_cvt_emb(const float* __restrict__ emb,
                                                 ushort* __restrict__ embf) {
    const int v = blockIdx.x;
    const int c = threadIdx.x;
    float s = emb[(size_t)v * DMODEL + c];
    unsigned hi = f2bf(s);
    unsigned lo = f2bf(s - bf2f(hi));
    embf[(size_t)v * (2 * DMODEL) + c] = (ushort)hi;
    embf[(size_t)v * (2 * DMODEL) + DMODEL + c] = (ushort)lo;
}

// ---------------- weight fp32 [K,N] -> frag bf16 hi/lo ----------------
// frag layout: [N/16][2K/32][64][8]; lane l holds B[kf*32+(l>>4)*8+j][nf*16+(l&15)]
template<int K>
__global__ __launch_bounds__(256) void k_cvt_w(const float* __restrict__ W,
                                               ushort* __restrict__ F, int N) {
    constexpr int NKF = K / 32;
    const int t = blockIdx.x * 256 + threadIdx.x;
    const int l = t & 63;
    const int cid = t >> 6;
    const int kf = cid % NKF;
    const int nf = cid / NKF;
    const int col = nf * 16 + (l & 15);
    const int k0 = kf * 32 + (l >> 4) * 8;
    float s[8];
#pragma unroll
    for (int j = 0; j < 8; ++j) s[j] = W[(size_t)(k0 + j) * N + col];
    unsigned hi[8], lo[8];
#pragma unroll
    for (int j = 0; j < 8; ++j) {
        hi[j] = f2bf(s[j]);
        lo[j] = f2bf(s[j] - bf2f(hi[j]));
    }
    uint4 ph = make_uint4(hi[0] | (hi[1] << 16), hi[2] | (hi[3] << 16),
                          hi[4] | (hi[5] << 16), hi[6] | (hi[7] << 16));
    uint4 pl = make_uint4(lo[0] | (lo[1] << 16), lo[2] | (lo[3] << 16),
                          lo[4] | (lo[5] << 16), lo[6] | (lo[7] << 16));
    size_t ohi = ((size_t)nf * (2 * NKF) + kf) * 512 + l * 8;
    *(uint4*)&F[ohi] = ph;
    *(uint4*)&F[ohi + (size_t)NKF * 512] = pl;
}

// ---------------- bf16 MFMA GEMM: A row-major bf16 [M][KE] (per-lane gather), B frag ----------------
template<int SPLITK, bool IDS>
__global__ __launch_bounds__(256) void k_mgemm(const ushort* __restrict__ A,
                                               const ushort* __restrict__ Bf,
                                               float* __restrict__ C,
                                               int M, int N, int KE,
                                               const int* __restrict__ ids) {
    __shared__ __align__(16) ushort As[8 * 512];
    __shared__ __align__(16) ushort Bs[8 * 512];
    const int tid = threadIdx.x;
    const int w = tid >> 6, lane = tid & 63;
    const int n0 = blockIdx.x * 128, m0 = blockIdx.y * 128;
    const int nkf = KE >> 5;
    const int KT = nkf / SPLITK;
    const int kt0 = blockIdx.z * KT;
    const int wm = w & 1, wn = w >> 1;
    const int c0 = 2 * w, c1 = c0 + 1;

    f32x4 acc[4][4] = {};

    int row0 = m0 + c0 * 16 + (lane & 15);
    int row1 = m0 + c1 * 16 + (lane & 15);
    if (IDS) { row0 = ids[row0]; row1 = ids[row1]; }
    const ushort* Ap0 = A + (size_t)row0 * KE + (lane >> 4) * 8;
    const ushort* Ap1 = A + (size_t)row1 * KE + (lane >> 4) * 8;
    const ushort* Bb0 = Bf + ((size_t)(n0 / 16 + c0) * nkf) * 512 + lane * 8;
    const ushort* Bb1 = Bf + ((size_t)(n0 / 16 + c1) * nkf) * 512 + lane * 8;
    ushort* As0 = As + c0 * 512 + lane * 8;
    ushort* As1 = As + c1 * 512 + lane * 8;
    ushort* Bs0 = Bs + c0 * 512 + lane * 8;
    ushort* Bs1 = Bs + c1 * 512 + lane * 8;

    for (int kt = kt0; kt < kt0 + KT; ++kt) {
        __builtin_amdgcn_global_load_lds((const __attribute__((address_space(1))) void*)(Ap0 + kt * 32),
                                         (__attribute__((address_space(3))) void*)As0, 16, 0, 0);
        __builtin_amdgcn_global_load_lds((const __attribute__((address_space(1))) void*)(Ap1 + kt * 32),
                                         (__attribute__((address_space(3))) void*)As1, 16, 0, 0);
        __builtin_amdgcn_global_load_lds((const __attribute__((address_space(1))) void*)(Bb0 + (size_t)kt * 512),
                                         (__attribute__((address_space(3))) void*)Bs0, 16, 0, 0);
        __builtin_amdgcn_global_load_lds((const __attribute__((address_space(1))) void*)(Bb1 + (size_t)kt * 512),
                                         (__attribute__((address_space(3))) void*)Bs1, 16, 0, 0);
        __syncthreads();
        short8 av[4], bv[4];
#pragma unroll
        for (int i = 0; i < 4; ++i)
            av[i] = *(const short8*)&As[(wm * 4 + i) * 512 + lane * 8];
#pragma unroll
        for (int i = 0; i < 4; ++i)
            bv[i] = *(const short8*)&Bs[(wn * 4 + i) * 512 + lane * 8];
#pragma unroll
        for (int mi = 0; mi < 4; ++mi)
#pragma unroll
            for (int ni = 0; ni < 4; ++ni)
                acc[mi][ni] = __builtin_amdgcn_mfma_f32_16x16x32_bf16(av[mi], bv[ni],
                                                                      acc[mi][ni], 0, 0, 0);
        __syncthreads();
    }

    // C/D layout (m89-verified): col = lane&15, row = (lane>>4)*4 + reg
    float* Cw = C + (size_t)blockIdx.z * ((size_t)M * N);
    const int r0 = (lane >> 4) * 4, cc = lane & 15;
#pragma unroll
    for (int mi = 0; mi < 4; ++mi)
#pragma unroll
        for (int r = 0; r < 4; ++r) {
            const int row = m0 + wm * 64 + mi * 16 + r0 + r;
            float* crow = &Cw[(size_t)row * N + n0 + wn * 64 + cc];
#pragma unroll
            for (int ni = 0; ni < 4; ++ni) crow[ni * 16] = acc[mi][ni][r];
        }
}

// sum 4 M*N slabs; TOBF: write bf16 hi|lo row-major [BL][2*DMODEL] instead of fp32
template<bool TOBF>
__global__ __launch_bounds__(256) void k_red4(const float* __restrict__ p,
                                              float* __restrict__ o,
                                              ushort* __restrict__ xb, int n4) {
    int i = blockIdx.x * 256 + threadIdx.x;
    const float4* p4 = (const float4*)p;
    float4 a = p4[i], b = p4[i + n4], c = p4[i + 2 * n4], d = p4[i + 3 * n4];
    float4 r = make_float4(a.x + b.x + c.x + d.x, a.y + b.y + c.y + d.y,
                           a.z + b.z + c.z + d.z, a.w + b.w + c.w + d.w);
    if (TOBF) {
        const int e0 = i * 4;
        const int bl = e0 >> 8;
        const int cl = e0 & 255;
        float s[4] = {r.x, r.y, r.z, r.w};
        unsigned hi[4], lo[4];
#pragma unroll
        for (int j = 0; j < 4; ++j) {
            hi[j] = f2bf(s[j]);
            lo[j] = f2bf(s[j] - bf2f(hi[j]));
        }
        *(uint2*)&xb[(size_t)bl * 512 + cl] =
            make_uint2(hi[0] | (hi[1] << 16), hi[2] | (hi[3] << 16));
        *(uint2*)&xb[(size_t)bl * 512 + 256 + cl] =
            make_uint2(lo[0] | (lo[1] << 16), lo[2] | (lo[3] << 16));
    } else {
        ((float4*)o)[i] = r;
    }
}

// ---------------- fused conv+SiLU + x_proj + delta (16 tokens/block, 512 blocks) ----------------
__global__ __launch_bounds__(256) void k_xpd(const float* __restrict__ xz,
                                             const float* __restrict__ cw,
                                             const float* __restrict__ cb,
                                             const float* __restrict__ w_xp,
                                             const float* __restrict__ w_dt,
                                             const float* __restrict__ b_dt,
                                             float* __restrict__ u,
                                             float* __restrict__ Bm,
                                             float* __restrict__ Cm,
                                             float* __restrict__ delta) {
    const int tid = threadIdx.x;
    const int bl0 = blockIdx.x * 16;
    __shared__ float us[16 * DINNER];   // 32 KB
    __shared__ float wsx[128 * 48];     // 24 KB (one chunk of w_xp)
    __shared__ float dts[16][DTRANK];   // 1 KB

    // ---- phase 0: conv + SiLU for 16 tokens (each thread: channels tid, tid+256)
    {
        const int ch0 = tid, ch1 = 256 + tid;
        float4 cwA = *(const float4*)&cw[ch0 * 4];
        float4 cwB = *(const float4*)&cw[ch1 * 4];
        const float cbA = cb[ch0], cbB = cb[ch1];
        const int lbase = bl0 & (LL - 1);
#pragma unroll
        for (int m = 0; m < 16; ++m) {
            const int bl = bl0 + m;
            const int lpos = lbase + m;
            float aA = cbA, aB = cbB;
#pragma unroll
            for (int k = 0; k < DCONV; ++k) {
                int tt = lpos - (DCONV - 1) + k;
                if (tt >= 0) {
                    const float* xr = &xz[(size_t)(bl - (DCONV - 1) + k) * 2 * DINNER];
                    aA = fmaf(((const float*)&cwA)[k], xr[ch0], aA);
                    aB = fmaf(((const float*)&cwB)[k], xr[ch1], aB);
                }
            }
            float uA = aA * sigmoidf_(aA);
            float uB = aB * sigmoidf_(aB);
            us[m * DINNER + ch0] = uA;
            us[m * DINNER + ch1] = uB;
            u[(size_t)bl * DINNER + ch0] = uA;
            u[(size_t)bl * DINNER + ch1] = uB;
        }
    }

    const int mp = tid >> 5;
    const int jg = (tid >> 3) & 3;
    const int s  = tid & 7;
    const float* usm0 = &us[(mp * 2 + 0) * DINNER];
    const float* usm1 = &us[(mp * 2 + 1) * DINNER];

    float acc0[12] = {}, acc1[12] = {};
#pragma unroll 1
    for (int ck = 0; ck < 4; ++ck) {
        __syncthreads();   // us ready (ck=0); wsx consumers done (ck>0)
        {   // stage w_xp rows [ck*128, ck*128+128): 1536 float4
            const float4* wg = (const float4*)&w_xp[ck * 128 * 48];
            float4* wl = (float4*)wsx;
#pragma unroll
            for (int q = 0; q < 6; ++q) wl[tid + q * 256] = wg[tid + q * 256];
        }
        __syncthreads();
#pragma unroll
        for (int i = 0; i < 16; ++i) {
            const int kl = i * 8 + s;
            const float a0 = usm0[ck * 128 + kl];
            const float a1 = usm1[ck * 128 + kl];
            const float* wr = &wsx[kl * 48 + jg * 12];
            float4 w0 = *(const float4*)&wr[0];
            float4 w1 = *(const float4*)&wr[4];
            float4 w2 = *(const float4*)&wr[8];
            acc0[0]  = fmaf(a0, w0.x, acc0[0]);  acc1[0]  = fmaf(a1, w0.x, acc1[0]);
            acc0[1]  = fmaf(a0, w0.y, acc0[1]);  acc1[1]  = fmaf(a1, w0.y, acc1[1]);
            acc0[2]  = fmaf(a0, w0.z, acc0[2]);  acc1[2]  = fmaf(a1, w0.z, acc1[2]);
            acc0[3]  = fmaf(a0, w0.w, acc0[3]);  acc1[3]  = fmaf(a1, w0.w, acc1[3]);
            acc0[4]  = fmaf(a0, w1.x, acc0[4]);  acc1[4]  = fmaf(a1, w1.x, acc1[4]);
            acc0[5]  = fmaf(a0, w1.y, acc0[5]);  acc1[5]  = fmaf(a1, w1.y, acc1[5]);
            acc0[6]  = fmaf(a0, w1.z, acc0[6]);  acc1[6]  = fmaf(a1, w1.z, acc1[6]);
            acc0[7]  = fmaf(a0, w1.w, acc0[7]);  acc1[7]  = fmaf(a1, w1.w, acc1[7]);
            acc0[8]  = fmaf(a0, w2.x, acc0[8]);  acc1[8]  = fmaf(a1, w2.x, acc1[8]);
            acc0[9]  = fmaf(a0, w2.y, acc0[9]);  acc1[9]  = fmaf(a1, w2.y, acc1[9]);
            acc0[10] = fmaf(a0, w2.z, acc0[10]); acc1[10] = fmaf(a1, w2.z, acc1[10]);
            acc0[11] = fmaf(a0, w2.w, acc0[11]); acc1[11] = fmaf(a1, w2.w, acc1[11]);
        }
    }
    // butterfly reduce across the 8 k-slice lanes
#pragma unroll
    for (int off = 4; off >= 1; off >>= 1) {
#pragma unroll
        for (int j = 0; j < 12; ++j) {
            acc0[j] += __shfl_xor(acc0[j], off, 8);
            acc1[j] += __shfl_xor(acc1[j], off, 8);
        }
    }
    if (s < 6) {
        const int bl_a = bl0 + mp * 2 + 0;
        const int bl_b = bl0 + mp * 2 + 1;
#pragma unroll
        for (int q = 0; q < 2; ++q) {
            int j = jg * 12 + s * 2 + q;
            float v0 = acc0[s * 2 + q];
            float v1 = acc1[s * 2 + q];
            if (j < 16) {
                dts[mp * 2 + 0][j] = v0;
                dts[mp * 2 + 1][j] = v1;
            } else if (j < 32) {
                Bm[(size_t)bl_a * DSTATE + (j - 16)] = v0;
                Bm[(size_t)bl_b * DSTATE + (j - 16)] = v1;
            } else {
                Cm[(size_t)bl_a * DSTATE + (j - 32)] = v0;
                Cm[(size_t)bl_b * DSTATE + (j - 32)] = v1;
            }
        }
    }
    __syncthreads();

    // phase 2: delta = softplus(dt @ w_dt + b_dt); thread: 4 channels x 8 tokens
    const int c0 = (tid & 127) * 4;
    const int mb = (tid >> 7) * 8;
    float4 bd = *(const float4*)&b_dt[c0];
    float a0[8], a1[8], a2[8], a3[8];
#pragma unroll
    for (int t = 0; t < 8; ++t) { a0[t] = bd.x; a1[t] = bd.y; a2[t] = bd.z; a3[t] = bd.w; }
#pragma unroll
    for (int r = 0; r < DTRANK; ++r) {
        float4 w4 = *(const float4*)&w_dt[r * DINNER + c0];
#pragma unroll
        for (int t = 0; t < 8; ++t) {
            float f = dts[mb + t][r];
            a0[t] = fmaf(f, w4.x, a0[t]);
            a1[t] = fmaf(f, w4.y, a1[t]);
            a2[t] = fmaf(f, w4.z, a2[t]);
            a3[t] = fmaf(f, w4.w, a3[t]);
        }
    }
#pragma unroll
    for (int t = 0; t < 8; ++t) {
        float4 o;
        o.x = (a0[t] > 20.f) ? a0[t] : log1pf(__expf(a0[t]));
        o.y = (a1[t] > 20.f) ? a1[t] : log1pf(__expf(a1[t]));
        o.z = (a2[t] > 20.f) ? a2[t] : log1pf(__expf(a2[t]));
        o.w = (a3[t] > 20.f) ? a3[t] : log1pf(__expf(a3[t]));
        *(float4*)&delta[(size_t)(bl0 + mb + t) * DINNER + c0] = o;
    }
}

// ---------------- chunked selective scan, per-channel 16-state-in-registers ----------------
__global__ __launch_bounds__(256) void k_scan_a(const float* __restrict__ delta,
                                                const float* __restrict__ u,
                                                const float* __restrict__ Bm,
                                                const float* __restrict__ A_log,
                                                float* __restrict__ aprod,
                                                float* __restrict__ hend) {
    const int tid = threadIdx.x;
    const int bid = blockIdx.x;
    const int chalf = bid & 1;
    const int k = (bid >> 1) & (NCHUNK - 1);
    const int b = bid >> 7;
    const int c = chalf * 256 + tid;
    const int bl0 = b * LL + k * LC;

    __shared__ float Bs[LC * DSTATE];
    for (int i = tid; i < LC * DSTATE; i += 256) Bs[i] = Bm[(size_t)bl0 * DSTATE + i];
    __syncthreads();

    float Ac[DSTATE];
#pragma unroll
    for (int q = 0; q < 4; ++q) {
        float4 a = *(const float4*)&A_log[c * DSTATE + q * 4];
        Ac[q * 4 + 0] = -__expf(a.x); Ac[q * 4 + 1] = -__expf(a.y);
        Ac[q * 4 + 2] = -__expf(a.z); Ac[q * 4 + 3] = -__expf(a.w);
    }

    float h[DSTATE] = {};
    float ap[DSTATE];
#pragma unroll
    for (int n = 0; n < DSTATE; ++n) ap[n] = 1.f;

    float dlt = delta[(size_t)bl0 * DINNER + c];
    float uu  = u[(size_t)bl0 * DINNER + c];
    for (int t = 0; t < LC; ++t) {
        float dlt2 = 0.f, uu2 = 0.f;
        if (t + 1 < LC) {
            dlt2 = delta[(size_t)(bl0 + t + 1) * DINNER + c];
            uu2  = u[(size_t)(bl0 + t + 1) * DINNER + c];
        }
        const float w = dlt * uu;
        const float4* Bs4 = (const float4*)&Bs[t * DSTATE];
        float4 b0 = Bs4[0], b1 = Bs4[1], b2 = Bs4[2], b3 = Bs4[3];
        float bv[DSTATE] = {b0.x, b0.y, b0.z, b0.w, b1.x, b1.y, b1.z, b1.w,
                            b2.x, b2.y, b2.z, b2.w, b3.x, b3.y, b3.z, b3.w};
#pragma unroll
        for (int n = 0; n < DSTATE; ++n) {
            float dA = __expf(dlt * Ac[n]);
            ap[n] *= dA;
            h[n] = fmaf(dA, h[n], w * bv[n]);
        }
        dlt = dlt2; uu = uu2;
    }
    size_t base = ((size_t)(k * BB + b) * DINNER + c) * DSTATE;
#pragma unroll
    for (int q = 0; q < 4; ++q) {
        *(float4*)&aprod[base + q * 4] = make_float4(ap[q*4], ap[q*4+1], ap[q*4+2], ap[q*4+3]);
        *(float4*)&hend[base + q * 4]  = make_float4(h[q*4],  h[q*4+1],  h[q*4+2],  h[q*4+3]);
    }
}

__global__ __launch_bounds__(256) void k_scan_b(const float* __restrict__ aprod,
                                                const float* __restrict__ hend,
                                                float* __restrict__ hstart) {
    int i = blockIdx.x * 256 + threadIdx.x;
    float h = 0.f;
#pragma unroll 4
    for (int k = 0; k < NCHUNK; ++k) {
        size_t idx = (size_t)k * NREC + i;
        float a = aprod[idx];
        float e = hend[idx];
        hstart[idx] = h;
        h = fmaf(a, h, e);
    }
}

// Pass C: re-scan chunk, emit gated output as bf16 hi|lo row-major [BL][2*DINNER]
__global__ __launch_bounds__(256) void k_scan_c(const float* __restrict__ delta,
                                                const float* __restrict__ u,
                                                const float* __restrict__ xz,
                                                const float* __restrict__ Bm,
                                                const float* __restrict__ Cm,
                                                const float* __restrict__ A_log,
                                                const float* __restrict__ Dp,
                                                const float* __restrict__ hstart,
                                                ushort* __restrict__ yb) {
    const int tid = threadIdx.x;
    const int bid = blockIdx.x;
    const int chalf = bid & 1;
    const int k = (bid >> 1) & (NCHUNK - 1);
    const int b = bid >> 7;
    const int c = chalf * 256 + tid;
    const int bl0 = b * LL + k * LC;

    __shared__ float Bs[LC * DSTATE];
    __shared__ float Cs[LC * DSTATE];
    for (int i = tid; i < LC * DSTATE; i += 256) {
        Bs[i] = Bm[(size_t)bl0 * DSTATE + i];
        Cs[i] = Cm[(size_t)bl0 * DSTATE + i];
    }
    __syncthreads();

    float Ac[DSTATE];
#pragma unroll
    for (int q = 0; q < 4; ++q) {
        float4 a = *(const float4*)&A_log[c * DSTATE + q * 4];
        Ac[q * 4 + 0] = -__expf(a.x); Ac[q * 4 + 1] = -__expf(a.y);
        Ac[q * 4 + 2] = -__expf(a.z); Ac[q * 4 + 3] = -__expf(a.w);
    }
    const float Dc = Dp[c];

    float h[DSTATE];
    size_t hbase = ((size_t)(k * BB + b) * DINNER + c) * DSTATE;
#pragma unroll
    for (int q = 0; q < 4; ++q) {
        float4 hv = *(const float4*)&hstart[hbase + q * 4];
        h[q*4] = hv.x; h[q*4+1] = hv.y; h[q*4+2] = hv.z; h[q*4+3] = hv.w;
    }

    float dlt = delta[(size_t)bl0 * DINNER + c];
    float uu  = u[(size_t)bl0 * DINNER + c];
    float rr  = xz[(size_t)bl0 * 2 * DINNER + DINNER + c];
    for (int t = 0; t < LC; ++t) {
        float dlt2 = 0.f, uu2 = 0.f, rr2 = 0.f;
        if (t + 1 < LC) {
            dlt2 = delta[(size_t)(bl0 + t + 1) * DINNER + c];
            uu2  = u[(size_t)(bl0 + t + 1) * DINNER + c];
            rr2  = xz[(size_t)(bl0 + t + 1) * 2 * DINNER + DINNER + c];
        }
        const float w = dlt * uu;
        const float4* Bs4 = (const float4*)&Bs[t * DSTATE];
        float4 b0 = Bs4[0], b1 = Bs4[1], b2 = Bs4[2], b3 = Bs4[3];
        float bv[DSTATE] = {b0.x, b0.y, b0.z, b0.w, b1.x, b1.y, b1.z, b1.w,
                            b2.x, b2.y, b2.z, b2.w, b3.x, b3.y, b3.z, b3.w};
        const float4* Cs4 = (const float4*)&Cs[t * DSTATE];
        float4 c0 = Cs4[0], c1 = Cs4[1], c2 = Cs4[2], c3 = Cs4[3];
        float cv[DSTATE] = {c0.x, c0.y, c0.z, c0.w, c1.x, c1.y, c1.z, c1.w,
                            c2.x, c2.y, c2.z, c2.w, c3.x, c3.y, c3.z, c3.w};
        float s0 = 0.f, s1 = 0.f, s2 = 0.f, s3 = 0.f;
#pragma unroll
        for (int n = 0; n < DSTATE; n += 4) {
            float dA0 = __expf(dlt * Ac[n+0]);
            float dA1 = __expf(dlt * Ac[n+1]);
            float dA2 = __expf(dlt * Ac[n+2]);
            float dA3 = __expf(dlt * Ac[n+3]);
            h[n+0] = fmaf(dA0, h[n+0], w * bv[n+0]);
            h[n+1] = fmaf(dA1, h[n+1], w * bv[n+1]);
            h[n+2] = fmaf(dA2, h[n+2], w * bv[n+2]);
            h[n+3] = fmaf(dA3, h[n+3], w * bv[n+3]);
            s0 = fmaf(h[n+0], cv[n+0], s0);
            s1 = fmaf(h[n+1], cv[n+1], s1);
            s2 = fmaf(h[n+2], cv[n+2], s2);
            s3 = fmaf(h[n+3], cv[n+3], s3);
        }
        float yv = (s0 + s1) + (s2 + s3) + uu * Dc;
        float yg = yv * (rr * sigmoidf_(rr));
        unsigned hi = f2bf(yg);
        unsigned lo = f2bf(yg - bf2f(hi));
        yb[(size_t)(bl0 + t) * (2 * DINNER) + c] = (ushort)hi;
        yb[(size_t)(bl0 + t) * (2 * DINNER) + DINNER + c] = (ushort)lo;
        dlt = dlt2; uu = uu2; rr = rr2;
    }
}

extern "C" void kernel_launch(void* const* d_in, const int* in_sizes, int n_in,
                              void* d_out, int out_size, void* d_ws, size_t ws_size,
                              hipStream_t stream) {
    const int*   ids   = (const int*)d_in[0];
    const float* emb   = (const float*)d_in[1];
    const float* w_in  = (const float*)d_in[2];
    const float* cw    = (const float*)d_in[3];
    const float* cb    = (const float*)d_in[4];
    const float* w_xp  = (const float*)d_in[5];
    const float* w_dt  = (const float*)d_in[6];
    const float* b_dt  = (const float*)d_in[7];
    const float* A_log = (const float*)d_in[8];
    const float* Dp    = (const float*)d_in[9];
    const float* w_out = (const float*)d_in[10];
    float* out = (float*)d_out;

    float* ws = (float*)d_ws;
    float* x    = ws;                              // BL*256  floats (xb bf16 / aprod overlay)
    float* xz   = x  + (size_t)BL * DMODEL;        // BL*1024 (also split-K partials)
    float* u    = xz + (size_t)BL * 2 * DINNER;    // BL*512
    float* Bm   = u  + (size_t)BL * DINNER;        // BL*16
    float* Cm   = Bm + (size_t)BL * DSTATE;        // BL*16
    float* dlt  = Cm + (size_t)BL * DSTATE;        // BL*512
    float* y    = dlt + (size_t)BL * DINNER;       // BL*512 floats = yb bf16 [BL][1024]
    float* hend = y + (size_t)BL * DINNER;         // NCHUNK*NREC = 2.10M
    float* wfif = hend + (size_t)NCHUNK * NREC;    // 262144 floats (w_in frag)
    float* wfof = wfif + 262144;                   // 131072 floats (w_out frag)
    float* embff = wfof + 131072;                  // 65536 floats (emb bf16 table)
    float* aprod  = x;
    float* hstart = aprod;
    ushort* xb   = (ushort*)x;      // [BL][512] hi|lo, written by red4<true> (layer 0)
    ushort* yb   = (ushort*)y;      // [BL][1024] hi|lo, written by scan_c
    ushort* wfi  = (ushort*)wfif;
    ushort* wfo  = (ushort*)wfof;
    ushort* embf = (ushort*)embff;  // [VOCAB][512] hi|lo

    k_cvt_emb<<<VOCAB, DMODEL, 0, stream>>>(emb, embf);

    for (int l = 0; l < NLAYER; ++l) {
        // ---- in_proj: xz = A @ w_in via split-bf16 MFMA (row-major A, per-lane gather)
        k_cvt_w<DMODEL><<<128, 256, 0, stream>>>(w_in + (size_t)l * DMODEL * 2 * DINNER,
                                                 wfi, 2 * DINNER);
        if (l == 0)
            k_mgemm<1, true><<<dim3(2 * DINNER / 128, BL / 128, 1), 256, 0, stream>>>(
                embf, wfi, xz, BL, 2 * DINNER, 2 * DMODEL, ids);
        else
            k_mgemm<1, false><<<dim3(2 * DINNER / 128, BL / 128, 1), 256, 0, stream>>>(
                xb, wfi, xz, BL, 2 * DINNER, 2 * DMODEL, ids);

        // ---- fused conv+silu + x_proj + delta
        k_xpd<<<BL / 16, 256, 0, stream>>>(xz, cw + l * DINNER * DCONV, cb + l * DINNER,
                                           w_xp + (size_t)l * DINNER * 48,
                                           w_dt + (size_t)l * DTRANK * DINNER,
                                           b_dt + (size_t)l * DINNER, u, Bm, Cm, dlt);

        const float* Al = A_log + (size_t)l * DINNER * DSTATE;
        k_scan_a<<<BB * NCHUNK * 2, 256, 0, stream>>>(dlt, u, Bm, Al, aprod, hend);
        k_scan_b<<<NREC / 256, 256, 0, stream>>>(aprod, hend, hstart);
        k_scan_c<<<BB * NCHUNK * 2, 256, 0, stream>>>(dlt, u, xz, Bm, Cm, Al,
                                                      Dp + (size_t)l * DINNER, hstart, yb);

        // ---- out_proj: dst = y @ w_out via split-bf16 MFMA, split-K=4 into xz
        k_cvt_w<DINNER><<<64, 256, 0, stream>>>(w_out + (size_t)l * DINNER * DMODEL,
                                                wfo, DMODEL);
        k_mgemm<4, false><<<dim3(DMODEL / 128, BL / 128, 4), 256, 0, stream>>>(
            yb, wfo, xz, BL, DMODEL, 2 * DINNER, ids);
        if (l == NLAYER - 1)
            k_red4<false><<<(BL * DMODEL / 4) / 256, 256, 0, stream>>>(xz, out, xb,
                                                                       BL * DMODEL / 4);
        else
            k_red4<true><<<(BL * DMODEL / 4) / 256, 256, 0, stream>>>(xz, out, xb,
                                                                      BL * DMODEL / 4);
    }
}

// Round 18
// 286.012 us; speedup vs baseline: 1.2763x; 1.0099x over previous
//
#include <hip/hip_runtime.h>
#include <math.h>

#define NLAYER 2
#define DMODEL 256
#define DINNER 512
#define DSTATE 16
#define DTRANK 16
#define DCONV  4
#define BB     4
#define LL     2048
#define BL     (BB*LL)
#define NCHUNK 64
#define LC     (LL/NCHUNK)          // 32
#define NREC   (BB*DINNER*DSTATE)   // 32768
#define VOCAB  256

typedef __attribute__((ext_vector_type(8))) short short8;   // 8 bf16 (4 VGPRs)
typedef __attribute__((ext_vector_type(4))) float f32x4;    // 4 fp32 acc

__device__ __forceinline__ float sigmoidf_(float x) { return 1.0f / (1.0f + __expf(-x)); }

// fp32 -> bf16 round-to-nearest-even (bit pattern) and back
__device__ __forceinline__ unsigned f2bf(float a) {
    unsigned u = __builtin_bit_cast(unsigned, a);
    return (u + 0x7fffu + ((u >> 16) & 1u)) >> 16;
}
__device__ __forceinline__ float bf2f(unsigned h) {
    return __builtin_bit_cast(float, h << 16);
}

// ---------------- weight fp32 [K,N] -> frag bf16 hi/lo (device body) ----------------
// frag layout: [N/16][2K/32][64][8]; lane l holds B[kf*32+(l>>4)*8+j][nf*16+(l&15)]
__device__ __forceinline__ void cvt_w_body(const float* __restrict__ W,
                                           ushort* __restrict__ F,
                                           int N, int NKF, int t) {
    const int l = t & 63;
    const int cid = t >> 6;
    const int kf = cid % NKF;
    const int nf = cid / NKF;
    const int col = nf * 16 + (l & 15);
    const int k0 = kf * 32 + (l >> 4) * 8;
    float s[8];
#pragma unroll
    for (int j = 0; j < 8; ++j) s[j] = W[(size_t)(k0 + j) * N + col];
    unsigned hi[8], lo[8];
#pragma unroll
    for (int j = 0; j < 8; ++j) {
        hi[j] = f2bf(s[j]);
        lo[j] = f2bf(s[j] - bf2f(hi[j]));
    }
    uint4 ph = make_uint4(hi[0] | (hi[1] << 16), hi[2] | (hi[3] << 16),
                          hi[4] | (hi[5] << 16), hi[6] | (hi[7] << 16));
    uint4 pl = make_uint4(lo[0] | (lo[1] << 16), lo[2] | (lo[3] << 16),
                          lo[4] | (lo[5] << 16), lo[6] | (lo[7] << 16));
    size_t ohi = ((size_t)nf * (2 * NKF) + kf) * 512 + l * 8;
    *(uint4*)&F[ohi] = ph;
    *(uint4*)&F[ohi + (size_t)NKF * 512] = pl;
}

// ---------------- all weight + embedding conversions in ONE launch ----------------
// blocks [0,128): w_in l0 -> wfi0 ; [128,256): w_in l1 -> wfi1
// blocks [256,320): w_out l0 -> wfo0 ; [320,384): w_out l1 -> wfo1
// blocks [384,448): emb -> embf bf16 hi|lo [VOCAB][512]
__global__ __launch_bounds__(256) void k_cvt_all(const float* __restrict__ emb,
                                                 const float* __restrict__ w_in,
                                                 const float* __restrict__ w_out,
                                                 ushort* __restrict__ embf,
                                                 ushort* __restrict__ wfi0,
                                                 ushort* __restrict__ wfi1,
                                                 ushort* __restrict__ wfo0,
                                                 ushort* __restrict__ wfo1) {
    const int bid = blockIdx.x;
    const int tid = threadIdx.x;
    if (bid < 128) {
        cvt_w_body(w_in, wfi0, 2 * DINNER, DMODEL / 32, bid * 256 + tid);
    } else if (bid < 256) {
        cvt_w_body(w_in + (size_t)DMODEL * 2 * DINNER, wfi1, 2 * DINNER, DMODEL / 32,
                   (bid - 128) * 256 + tid);
    } else if (bid < 320) {
        cvt_w_body(w_out, wfo0, DMODEL, DINNER / 32, (bid - 256) * 256 + tid);
    } else if (bid < 384) {
        cvt_w_body(w_out + (size_t)DINNER * DMODEL, wfo1, DMODEL, DINNER / 32,
                   (bid - 320) * 256 + tid);
    } else {
        const int idx = (bid - 384) * 256 + tid;   // 0..16383
        const int v  = idx >> 6;
        const int c0 = (idx & 63) * 4;
        float4 sv = *(const float4*)&emb[(size_t)v * DMODEL + c0];
        float s[4] = {sv.x, sv.y, sv.z, sv.w};
        unsigned hi[4], lo[4];
#pragma unroll
        for (int j = 0; j < 4; ++j) {
            hi[j] = f2bf(s[j]);
            lo[j] = f2bf(s[j] - bf2f(hi[j]));
        }
        *(uint2*)&embf[(size_t)v * 512 + c0] =
            make_uint2(hi[0] | (hi[1] << 16), hi[2] | (hi[3] << 16));
        *(uint2*)&embf[(size_t)v * 512 + 256 + c0] =
            make_uint2(lo[0] | (lo[1] << 16), lo[2] | (lo[3] << 16));
    }
}

// ---------------- bf16 MFMA GEMM: A row-major bf16 [M][KE] (per-lane gather), B frag ----------------
template<int SPLITK, bool IDS>
__global__ __launch_bounds__(256) void k_mgemm(const ushort* __restrict__ A,
                                               const ushort* __restrict__ Bf,
                                               float* __restrict__ C,
                                               int M, int N, int KE,
                                               const int* __restrict__ ids) {
    __shared__ __align__(16) ushort As[8 * 512];
    __shared__ __align__(16) ushort Bs[8 * 512];
    const int tid = threadIdx.x;
    const int w = tid >> 6, lane = tid & 63;
    const int n0 = blockIdx.x * 128, m0 = blockIdx.y * 128;
    const int nkf = KE >> 5;
    const int KT = nkf / SPLITK;
    const int kt0 = blockIdx.z * KT;
    const int wm = w & 1, wn = w >> 1;
    const int c0 = 2 * w, c1 = c0 + 1;

    f32x4 acc[4][4] = {};

    int row0 = m0 + c0 * 16 + (lane & 15);
    int row1 = m0 + c1 * 16 + (lane & 15);
    if (IDS) { row0 = ids[row0]; row1 = ids[row1]; }
    const ushort* Ap0 = A + (size_t)row0 * KE + (lane >> 4) * 8;
    const ushort* Ap1 = A + (size_t)row1 * KE + (lane >> 4) * 8;
    const ushort* Bb0 = Bf + ((size_t)(n0 / 16 + c0) * nkf) * 512 + lane * 8;
    const ushort* Bb1 = Bf + ((size_t)(n0 / 16 + c1) * nkf) * 512 + lane * 8;
    ushort* As0 = As + c0 * 512 + lane * 8;
    ushort* As1 = As + c1 * 512 + lane * 8;
    ushort* Bs0 = Bs + c0 * 512 + lane * 8;
    ushort* Bs1 = Bs + c1 * 512 + lane * 8;

    for (int kt = kt0; kt < kt0 + KT; ++kt) {
        __builtin_amdgcn_global_load_lds((const __attribute__((address_space(1))) void*)(Ap0 + kt * 32),
                                         (__attribute__((address_space(3))) void*)As0, 16, 0, 0);
        __builtin_amdgcn_global_load_lds((const __attribute__((address_space(1))) void*)(Ap1 + kt * 32),
                                         (__attribute__((address_space(3))) void*)As1, 16, 0, 0);
        __builtin_amdgcn_global_load_lds((const __attribute__((address_space(1))) void*)(Bb0 + (size_t)kt * 512),
                                         (__attribute__((address_space(3))) void*)Bs0, 16, 0, 0);
        __builtin_amdgcn_global_load_lds((const __attribute__((address_space(1))) void*)(Bb1 + (size_t)kt * 512),
                                         (__attribute__((address_space(3))) void*)Bs1, 16, 0, 0);
        __syncthreads();
        short8 av[4], bv[4];
#pragma unroll
        for (int i = 0; i < 4; ++i)
            av[i] = *(const short8*)&As[(wm * 4 + i) * 512 + lane * 8];
#pragma unroll
        for (int i = 0; i < 4; ++i)
            bv[i] = *(const short8*)&Bs[(wn * 4 + i) * 512 + lane * 8];
#pragma unroll
        for (int mi = 0; mi < 4; ++mi)
#pragma unroll
            for (int ni = 0; ni < 4; ++ni)
                acc[mi][ni] = __builtin_amdgcn_mfma_f32_16x16x32_bf16(av[mi], bv[ni],
                                                                      acc[mi][ni], 0, 0, 0);
        __syncthreads();
    }

    // C/D layout (m89-verified): col = lane&15, row = (lane>>4)*4 + reg
    float* Cw = C + (size_t)blockIdx.z * ((size_t)M * N);
    const int r0 = (lane >> 4) * 4, cc = lane & 15;
#pragma unroll
    for (int mi = 0; mi < 4; ++mi)
#pragma unroll
        for (int r = 0; r < 4; ++r) {
            const int row = m0 + wm * 64 + mi * 16 + r0 + r;
            float* crow = &Cw[(size_t)row * N + n0 + wn * 64 + cc];
#pragma unroll
            for (int ni = 0; ni < 4; ++ni) crow[ni * 16] = acc[mi][ni][r];
        }
}

// sum 4 M*N slabs; TOBF: write bf16 hi|lo row-major [BL][2*DMODEL] instead of fp32
template<bool TOBF>
__global__ __launch_bounds__(256) void k_red4(const float* __restrict__ p,
                                              float* __restrict__ o,
                                              ushort* __restrict__ xb, int n4) {
    int i = blockIdx.x * 256 + threadIdx.x;
    const float4* p4 = (const float4*)p;
    float4 a = p4[i], b = p4[i + n4], c = p4[i + 2 * n4], d = p4[i + 3 * n4];
    float4 r = make_float4(a.x + b.x + c.x + d.x, a.y + b.y + c.y + d.y,
                           a.z + b.z + c.z + d.z, a.w + b.w + c.w + d.w);
    if (TOBF) {
        const int e0 = i * 4;
        const int bl = e0 >> 8;
        const int cl = e0 & 255;
        float s[4] = {r.x, r.y, r.z, r.w};
        unsigned hi[4], lo[4];
#pragma unroll
        for (int j = 0; j < 4; ++j) {
            hi[j] = f2bf(s[j]);
            lo[j] = f2bf(s[j] - bf2f(hi[j]));
        }
        *(uint2*)&xb[(size_t)bl * 512 + cl] =
            make_uint2(hi[0] | (hi[1] << 16), hi[2] | (hi[3] << 16));
        *(uint2*)&xb[(size_t)bl * 512 + 256 + cl] =
            make_uint2(lo[0] | (lo[1] << 16), lo[2] | (lo[3] << 16));
    } else {
        ((float4*)o)[i] = r;
    }
}

// ---------------- fused conv+SiLU + x_proj + delta (16 tokens/block, K-chunked conv) ----------------
// Per chunk ck: conv+SiLU for channels [ck*128,(ck+1)*128) of 16 tokens into an
// 8 KB us tile (+ u global), stage w_xp chunk (24 KB, stride 48 = measured
// conflict-free), then the r10 FMA block. LDS total 33 KB -> 4 blocks/CU.
// FMA order identical to round 10 -> bitwise-same outputs.
__global__ __launch_bounds__(256) void k_xpd(const float* __restrict__ xz,
                                             const float* __restrict__ cw,
                                             const float* __restrict__ cb,
                                             const float* __restrict__ w_xp,
                                             const float* __restrict__ w_dt,
                                             const float* __restrict__ b_dt,
                                             float* __restrict__ u,
                                             float* __restrict__ Bm,
                                             float* __restrict__ Cm,
                                             float* __restrict__ delta) {
    const int tid = threadIdx.x;
    const int bl0 = blockIdx.x * 16;
    __shared__ float us[16 * 128];      // 8 KB: current 128-channel chunk of u
    __shared__ float wsx[128 * 48];     // 24 KB
    __shared__ float dts[16][DTRANK];   // 1 KB

    const int mp = tid >> 5;
    const int jg = (tid >> 3) & 3;
    const int s  = tid & 7;
    const int chl = tid & 127;          // channel within chunk (conv)
    const int mh  = (tid >> 7) * 8;     // token half (conv)
    const int lbase = bl0 & (LL - 1);

    float acc0[12] = {}, acc1[12] = {};
#pragma unroll 1
    for (int ck = 0; ck < 4; ++ck) {
        __syncthreads();   // previous FMA done with us & wsx
        {   // conv + SiLU: channel ch, tokens [mh, mh+8)
            const int ch = ck * 128 + chl;
            float4 cwv = *(const float4*)&cw[ch * 4];
            const float cbv = cb[ch];
#pragma unroll
            for (int m = 0; m < 8; ++m) {
                const int bl = bl0 + mh + m;
                const int lpos = lbase + mh + m;
                float a = cbv;
#pragma unroll
                for (int k = 0; k < DCONV; ++k) {
                    int tt = lpos - (DCONV - 1) + k;
                    if (tt >= 0)
                        a = fmaf(((const float*)&cwv)[k],
                                 xz[(size_t)(bl - (DCONV - 1) + k) * 2 * DINNER + ch], a);
                }
                float uv = a * sigmoidf_(a);
                us[(mh + m) * 128 + chl] = uv;
                u[(size_t)bl * DINNER + ch] = uv;
            }
        }
        {   // stage w_xp rows [ck*128, ck*128+128): 1536 float4
            const float4* wg = (const float4*)&w_xp[ck * 128 * 48];
            float4* wl = (float4*)wsx;
#pragma unroll
            for (int q = 0; q < 6; ++q) wl[tid + q * 256] = wg[tid + q * 256];
        }
        __syncthreads();
        const float* usm0 = &us[(mp * 2 + 0) * 128];
        const float* usm1 = &us[(mp * 2 + 1) * 128];
#pragma unroll
        for (int i = 0; i < 16; ++i) {
            const int kl = i * 8 + s;
            const float a0 = usm0[kl];
            const float a1 = usm1[kl];
            const float* wr = &wsx[kl * 48 + jg * 12];
            float4 w0 = *(const float4*)&wr[0];
            float4 w1 = *(const float4*)&wr[4];
            float4 w2 = *(const float4*)&wr[8];
            acc0[0]  = fmaf(a0, w0.x, acc0[0]);  acc1[0]  = fmaf(a1, w0.x, acc1[0]);
            acc0[1]  = fmaf(a0, w0.y, acc0[1]);  acc1[1]  = fmaf(a1, w0.y, acc1[1]);
            acc0[2]  = fmaf(a0, w0.z, acc0[2]);  acc1[2]  = fmaf(a1, w0.z, acc1[2]);
            acc0[3]  = fmaf(a0, w0.w, acc0[3]);  acc1[3]  = fmaf(a1, w0.w, acc1[3]);
            acc0[4]  = fmaf(a0, w1.x, acc0[4]);  acc1[4]  = fmaf(a1, w1.x, acc1[4]);
            acc0[5]  = fmaf(a0, w1.y, acc0[5]);  acc1[5]  = fmaf(a1, w1.y, acc1[5]);
            acc0[6]  = fmaf(a0, w1.z, acc0[6]);  acc1[6]  = fmaf(a1, w1.z, acc1[6]);
            acc0[7]  = fmaf(a0, w1.w, acc0[7]);  acc1[7]  = fmaf(a1, w1.w, acc1[7]);
            acc0[8]  = fmaf(a0, w2.x, acc0[8]);  acc1[8]  = fmaf(a1, w2.x, acc1[8]);
            acc0[9]  = fmaf(a0, w2.y, acc0[9]);  acc1[9]  = fmaf(a1, w2.y, acc1[9]);
            acc0[10] = fmaf(a0, w2.z, acc0[10]); acc1[10] = fmaf(a1, w2.z, acc1[10]);
            acc0[11] = fmaf(a0, w2.w, acc0[11]); acc1[11] = fmaf(a1, w2.w, acc1[11]);
        }
    }
    // butterfly reduce across the 8 k-slice lanes
#pragma unroll
    for (int off = 4; off >= 1; off >>= 1) {
#pragma unroll
        for (int j = 0; j < 12; ++j) {
            acc0[j] += __shfl_xor(acc0[j], off, 8);
            acc1[j] += __shfl_xor(acc1[j], off, 8);
        }
    }
    if (s < 6) {
        const int bl_a = bl0 + mp * 2 + 0;
        const int bl_b = bl0 + mp * 2 + 1;
#pragma unroll
        for (int q = 0; q < 2; ++q) {
            int j = jg * 12 + s * 2 + q;
            float v0 = acc0[s * 2 + q];
            float v1 = acc1[s * 2 + q];
            if (j < 16) {
                dts[mp * 2 + 0][j] = v0;
                dts[mp * 2 + 1][j] = v1;
            } else if (j < 32) {
                Bm[(size_t)bl_a * DSTATE + (j - 16)] = v0;
                Bm[(size_t)bl_b * DSTATE + (j - 16)] = v1;
            } else {
                Cm[(size_t)bl_a * DSTATE + (j - 32)] = v0;
                Cm[(size_t)bl_b * DSTATE + (j - 32)] = v1;
            }
        }
    }
    __syncthreads();

    // phase 2: delta = softplus(dt @ w_dt + b_dt); thread: 4 channels x 8 tokens
    const int c0 = (tid & 127) * 4;
    const int mb = (tid >> 7) * 8;
    float4 bd = *(const float4*)&b_dt[c0];
    float a0[8], a1[8], a2[8], a3[8];
#pragma unroll
    for (int t = 0; t < 8; ++t) { a0[t] = bd.x; a1[t] = bd.y; a2[t] = bd.z; a3[t] = bd.w; }
#pragma unroll
    for (int r = 0; r < DTRANK; ++r) {
        float4 w4 = *(const float4*)&w_dt[r * DINNER + c0];
#pragma unroll
        for (int t = 0; t < 8; ++t) {
            float f = dts[mb + t][r];
            a0[t] = fmaf(f, w4.x, a0[t]);
            a1[t] = fmaf(f, w4.y, a1[t]);
            a2[t] = fmaf(f, w4.z, a2[t]);
            a3[t] = fmaf(f, w4.w, a3[t]);
        }
    }
#pragma unroll
    for (int t = 0; t < 8; ++t) {
        float4 o;
        o.x = (a0[t] > 20.f) ? a0[t] : log1pf(__expf(a0[t]));
        o.y = (a1[t] > 20.f) ? a1[t] : log1pf(__expf(a1[t]));
        o.z = (a2[t] > 20.f) ? a2[t] : log1pf(__expf(a2[t]));
        o.w = (a3[t] > 20.f) ? a3[t] : log1pf(__expf(a3[t]));
        *(float4*)&delta[(size_t)(bl0 + mb + t) * DINNER + c0] = o;
    }
}

// ---------------- chunked selective scan, per-channel 16-state-in-registers ----------------
__global__ __launch_bounds__(256) void k_scan_a(const float* __restrict__ delta,
                                                const float* __restrict__ u,
                                                const float* __restrict__ Bm,
                                                const float* __restrict__ A_log,
                                                float* __restrict__ aprod,
                                                float* __restrict__ hend) {
    const int tid = threadIdx.x;
    const int bid = blockIdx.x;
    const int chalf = bid & 1;
    const int k = (bid >> 1) & (NCHUNK - 1);
    const int b = bid >> 7;
    const int c = chalf * 256 + tid;
    const int bl0 = b * LL + k * LC;

    __shared__ float Bs[LC * DSTATE];
    for (int i = tid; i < LC * DSTATE; i += 256) Bs[i] = Bm[(size_t)bl0 * DSTATE + i];
    __syncthreads();

    float Ac[DSTATE];
#pragma unroll
    for (int q = 0; q < 4; ++q) {
        float4 a = *(const float4*)&A_log[c * DSTATE + q * 4];
        Ac[q * 4 + 0] = -__expf(a.x); Ac[q * 4 + 1] = -__expf(a.y);
        Ac[q * 4 + 2] = -__expf(a.z); Ac[q * 4 + 3] = -__expf(a.w);
    }

    float h[DSTATE] = {};
    float ap[DSTATE];
#pragma unroll
    for (int n = 0; n < DSTATE; ++n) ap[n] = 1.f;

    float dlt = delta[(size_t)bl0 * DINNER + c];
    float uu  = u[(size_t)bl0 * DINNER + c];
    for (int t = 0; t < LC; ++t) {
        float dlt2 = 0.f, uu2 = 0.f;
        if (t + 1 < LC) {
            dlt2 = delta[(size_t)(bl0 + t + 1) * DINNER + c];
            uu2  = u[(size_t)(bl0 + t + 1) * DINNER + c];
        }
        const float w = dlt * uu;
        const float4* Bs4 = (const float4*)&Bs[t * DSTATE];
        float4 b0 = Bs4[0], b1 = Bs4[1], b2 = Bs4[2], b3 = Bs4[3];
        float bv[DSTATE] = {b0.x, b0.y, b0.z, b0.w, b1.x, b1.y, b1.z, b1.w,
                            b2.x, b2.y, b2.z, b2.w, b3.x, b3.y, b3.z, b3.w};
#pragma unroll
        for (int n = 0; n < DSTATE; ++n) {
            float dA = __expf(dlt * Ac[n]);
            ap[n] *= dA;
            h[n] = fmaf(dA, h[n], w * bv[n]);
        }
        dlt = dlt2; uu = uu2;
    }
    size_t base = ((size_t)(k * BB + b) * DINNER + c) * DSTATE;
#pragma unroll
    for (int q = 0; q < 4; ++q) {
        *(float4*)&aprod[base + q * 4] = make_float4(ap[q*4], ap[q*4+1], ap[q*4+2], ap[q*4+3]);
        *(float4*)&hend[base + q * 4]  = make_float4(h[q*4],  h[q*4+1],  h[q*4+2],  h[q*4+3]);
    }
}

__global__ __launch_bounds__(256) void k_scan_b(const float* __restrict__ aprod,
                                                const float* __restrict__ hend,
                                                float* __restrict__ hstart) {
    int i = blockIdx.x * 256 + threadIdx.x;
    float h = 0.f;
#pragma unroll 4
    for (int k = 0; k < NCHUNK; ++k) {
        size_t idx = (size_t)k * NREC + i;
        float a = aprod[idx];
        float e = hend[idx];
        hstart[idx] = h;
        h = fmaf(a, h, e);
    }
}

// Pass C: re-scan chunk, emit gated output as bf16 hi|lo row-major [BL][2*DINNER]
__global__ __launch_bounds__(256) void k_scan_c(const float* __restrict__ delta,
                                                const float* __restrict__ u,
                                                const float* __restrict__ xz,
                                                const float* __restrict__ Bm,
                                                const float* __restrict__ Cm,
                                                const float* __restrict__ A_log,
                                                const float* __restrict__ Dp,
                                                const float* __restrict__ hstart,
                                                ushort* __restrict__ yb) {
    const int tid = threadIdx.x;
    const int bid = blockIdx.x;
    const int chalf = bid & 1;
    const int k = (bid >> 1) & (NCHUNK - 1);
    const int b = bid >> 7;
    const int c = chalf * 256 + tid;
    const int bl0 = b * LL + k * LC;

    __shared__ float Bs[LC * DSTATE];
    __shared__ float Cs[LC * DSTATE];
    for (int i = tid; i < LC * DSTATE; i += 256) {
        Bs[i] = Bm[(size_t)bl0 * DSTATE + i];
        Cs[i] = Cm[(size_t)bl0 * DSTATE + i];
    }
    __syncthreads();

    float Ac[DSTATE];
#pragma unroll
    for (int q = 0; q < 4; ++q) {
        float4 a = *(const float4*)&A_log[c * DSTATE + q * 4];
        Ac[q * 4 + 0] = -__expf(a.x); Ac[q * 4 + 1] = -__expf(a.y);
        Ac[q * 4 + 2] = -__expf(a.z); Ac[q * 4 + 3] = -__expf(a.w);
    }
    const float Dc = Dp[c];

    float h[DSTATE];
    size_t hbase = ((size_t)(k * BB + b) * DINNER + c) * DSTATE;
#pragma unroll
    for (int q = 0; q < 4; ++q) {
        float4 hv = *(const float4*)&hstart[hbase + q * 4];
        h[q*4] = hv.x; h[q*4+1] = hv.y; h[q*4+2] = hv.z; h[q*4+3] = hv.w;
    }

    float dlt = delta[(size_t)bl0 * DINNER + c];
    float uu  = u[(size_t)bl0 * DINNER + c];
    float rr  = xz[(size_t)bl0 * 2 * DINNER + DINNER + c];
    for (int t = 0; t < LC; ++t) {
        float dlt2 = 0.f, uu2 = 0.f, rr2 = 0.f;
        if (t + 1 < LC) {
            dlt2 = delta[(size_t)(bl0 + t + 1) * DINNER + c];
            uu2  = u[(size_t)(bl0 + t + 1) * DINNER + c];
            rr2  = xz[(size_t)(bl0 + t + 1) * 2 * DINNER + DINNER + c];
        }
        const float w = dlt * uu;
        const float4* Bs4 = (const float4*)&Bs[t * DSTATE];
        float4 b0 = Bs4[0], b1 = Bs4[1], b2 = Bs4[2], b3 = Bs4[3];
        float bv[DSTATE] = {b0.x, b0.y, b0.z, b0.w, b1.x, b1.y, b1.z, b1.w,
                            b2.x, b2.y, b2.z, b2.w, b3.x, b3.y, b3.z, b3.w};
        const float4* Cs4 = (const float4*)&Cs[t * DSTATE];
        float4 c0 = Cs4[0], c1 = Cs4[1], c2 = Cs4[2], c3 = Cs4[3];
        float cv[DSTATE] = {c0.x, c0.y, c0.z, c0.w, c1.x, c1.y, c1.z, c1.w,
                            c2.x, c2.y, c2.z, c2.w, c3.x, c3.y, c3.z, c3.w};
        float s0 = 0.f, s1 = 0.f, s2 = 0.f, s3 = 0.f;
#pragma unroll
        for (int n = 0; n < DSTATE; n += 4) {
            float dA0 = __expf(dlt * Ac[n+0]);
            float dA1 = __expf(dlt * Ac[n+1]);
            float dA2 = __expf(dlt * Ac[n+2]);
            float dA3 = __expf(dlt * Ac[n+3]);
            h[n+0] = fmaf(dA0, h[n+0], w * bv[n+0]);
            h[n+1] = fmaf(dA1, h[n+1], w * bv[n+1]);
            h[n+2] = fmaf(dA2, h[n+2], w * bv[n+2]);
            h[n+3] = fmaf(dA3, h[n+3], w * bv[n+3]);
            s0 = fmaf(h[n+0], cv[n+0], s0);
            s1 = fmaf(h[n+1], cv[n+1], s1);
            s2 = fmaf(h[n+2], cv[n+2], s2);
            s3 = fmaf(h[n+3], cv[n+3], s3);
        }
        float yv = (s0 + s1) + (s2 + s3) + uu * Dc;
        float yg = yv * (rr * sigmoidf_(rr));
        unsigned hi = f2bf(yg);
        unsigned lo = f2bf(yg - bf2f(hi));
        yb[(size_t)(bl0 + t) * (2 * DINNER) + c] = (ushort)hi;
        yb[(size_t)(bl0 + t) * (2 * DINNER) + DINNER + c] = (ushort)lo;
        dlt = dlt2; uu = uu2; rr = rr2;
    }
}

extern "C" void kernel_launch(void* const* d_in, const int* in_sizes, int n_in,
                              void* d_out, int out_size, void* d_ws, size_t ws_size,
                              hipStream_t stream) {
    const int*   ids   = (const int*)d_in[0];
    const float* emb   = (const float*)d_in[1];
    const float* w_in  = (const float*)d_in[2];
    const float* cw    = (const float*)d_in[3];
    const float* cb    = (const float*)d_in[4];
    const float* w_xp  = (const float*)d_in[5];
    const float* w_dt  = (const float*)d_in[6];
    const float* b_dt  = (const float*)d_in[7];
    const float* A_log = (const float*)d_in[8];
    const float* Dp    = (const float*)d_in[9];
    const float* w_out = (const float*)d_in[10];
    float* out = (float*)d_out;

    float* ws = (float*)d_ws;
    float* x    = ws;                              // BL*256  floats (xb bf16 / aprod overlay)
    float* xz   = x  + (size_t)BL * DMODEL;        // BL*1024 (also split-K partials)
    float* u    = xz + (size_t)BL * 2 * DINNER;    // BL*512
    float* Bm   = u  + (size_t)BL * DINNER;        // BL*16
    float* Cm   = Bm + (size_t)BL * DSTATE;        // BL*16
    float* dlt  = Cm + (size_t)BL * DSTATE;        // BL*512
    float* y    = dlt + (size_t)BL * DINNER;       // BL*512 floats = yb bf16 [BL][1024]
    float* hend = y + (size_t)BL * DINNER;         // NCHUNK*NREC = 2.10M
    float* wfi0f = hend + (size_t)NCHUNK * NREC;   // 262144 floats (w_in frag l0)
    float* wfi1f = wfi0f + 262144;                 // 262144 floats (w_in frag l1)
    float* wfo0f = wfi1f + 262144;                 // 131072 floats (w_out frag l0)
    float* wfo1f = wfo0f + 131072;                 // 131072 floats (w_out frag l1)
    float* embff = wfo1f + 131072;                 // 65536 floats (emb bf16 table)
    float* aprod  = x;
    float* hstart = aprod;
    ushort* xb   = (ushort*)x;      // [BL][512] hi|lo, written by red4<true> (layer 0)
    ushort* yb   = (ushort*)y;      // [BL][1024] hi|lo, written by scan_c
    ushort* wfi[2] = {(ushort*)wfi0f, (ushort*)wfi1f};
    ushort* wfo[2] = {(ushort*)wfo0f, (ushort*)wfo1f};
    ushort* embf = (ushort*)embff;  // [VOCAB][512] hi|lo

    // all weight + embedding conversions in one launch
    k_cvt_all<<<448, 256, 0, stream>>>(emb, w_in, w_out, embf,
                                       wfi[0], wfi[1], wfo[0], wfo[1]);

    for (int l = 0; l < NLAYER; ++l) {
        // ---- in_proj: xz = A @ w_in via split-bf16 MFMA (row-major A, per-lane gather)
        if (l == 0)
            k_mgemm<1, true><<<dim3(2 * DINNER / 128, BL / 128, 1), 256, 0, stream>>>(
                embf, wfi[0], xz, BL, 2 * DINNER, 2 * DMODEL, ids);
        else
            k_mgemm<1, false><<<dim3(2 * DINNER / 128, BL / 128, 1), 256, 0, stream>>>(
                xb, wfi[1], xz, BL, 2 * DINNER, 2 * DMODEL, ids);

        // ---- fused conv+silu + x_proj + delta (K-chunked conv, 33 KB LDS)
        k_xpd<<<BL / 16, 256, 0, stream>>>(xz, cw + l * DINNER * DCONV, cb + l * DINNER,
                                           w_xp + (size_t)l * DINNER * 48,
                                           w_dt + (size_t)l * DTRANK * DINNER,
                                           b_dt + (size_t)l * DINNER, u, Bm, Cm, dlt);

        const float* Al = A_log + (size_t)l * DINNER * DSTATE;
        k_scan_a<<<BB * NCHUNK * 2, 256, 0, stream>>>(dlt, u, Bm, Al, aprod, hend);
        k_scan_b<<<NREC / 256, 256, 0, stream>>>(aprod, hend, hstart);
        k_scan_c<<<BB * NCHUNK * 2, 256, 0, stream>>>(dlt, u, xz, Bm, Cm, Al,
                                                      Dp + (size_t)l * DINNER, hstart, yb);

        // ---- out_proj: dst = y @ w_out via split-bf16 MFMA, split-K=4 into xz
        k_mgemm<4, false><<<dim3(DMODEL / 128, BL / 128, 4), 256, 0, stream>>>(
            yb, wfo[l], xz, BL, DMODEL, 2 * DINNER, ids);
        if (l == NLAYER - 1)
            k_red4<false><<<(BL * DMODEL / 4) / 256, 256, 0, stream>>>(xz, out, xb,
                                                                       BL * DMODEL / 4);
        else
            k_red4<true><<<(BL * DMODEL / 4) / 256, 256, 0, stream>>>(xz, out, xb,
                                                                      BL * DMODEL / 4);
    }
}

// Round 19
// 278.792 us; speedup vs baseline: 1.3093x; 1.0259x over previous
//
#include <hip/hip_runtime.h>
#include <math.h>

#define NLAYER 2
#define DMODEL 256
#define DINNER 512
#define DSTATE 16
#define DTRANK 16
#define DCONV  4
#define BB     4
#define LL     2048
#define BL     (BB*LL)
#define NCHUNK 64
#define LC     (LL/NCHUNK)          // 32
#define NREC   (BB*DINNER*DSTATE)   // 32768
#define VOCAB  256

typedef __attribute__((ext_vector_type(8))) short short8;   // 8 bf16 (4 VGPRs)
typedef __attribute__((ext_vector_type(4))) float f32x4;    // 4 fp32 acc

__device__ __forceinline__ float sigmoidf_(float x) { return 1.0f / (1.0f + __expf(-x)); }

// fp32 -> bf16 round-to-nearest-even (bit pattern) and back
__device__ __forceinline__ unsigned f2bf(float a) {
    unsigned u = __builtin_bit_cast(unsigned, a);
    return (u + 0x7fffu + ((u >> 16) & 1u)) >> 16;
}
__device__ __forceinline__ float bf2f(unsigned h) {
    return __builtin_bit_cast(float, h << 16);
}

// ---------------- weight fp32 [K,N] -> frag bf16 hi/lo (device body) ----------------
// frag layout: [N/16][2K/32][64][8]; lane l holds B[kf*32+(l>>4)*8+j][nf*16+(l&15)]
__device__ __forceinline__ void cvt_w_body(const float* __restrict__ W,
                                           ushort* __restrict__ F,
                                           int N, int NKF, int t) {
    const int l = t & 63;
    const int cid = t >> 6;
    const int kf = cid % NKF;
    const int nf = cid / NKF;
    const int col = nf * 16 + (l & 15);
    const int k0 = kf * 32 + (l >> 4) * 8;
    float s[8];
#pragma unroll
    for (int j = 0; j < 8; ++j) s[j] = W[(size_t)(k0 + j) * N + col];
    unsigned hi[8], lo[8];
#pragma unroll
    for (int j = 0; j < 8; ++j) {
        hi[j] = f2bf(s[j]);
        lo[j] = f2bf(s[j] - bf2f(hi[j]));
    }
    uint4 ph = make_uint4(hi[0] | (hi[1] << 16), hi[2] | (hi[3] << 16),
                          hi[4] | (hi[5] << 16), hi[6] | (hi[7] << 16));
    uint4 pl = make_uint4(lo[0] | (lo[1] << 16), lo[2] | (lo[3] << 16),
                          lo[4] | (lo[5] << 16), lo[6] | (lo[7] << 16));
    size_t ohi = ((size_t)nf * (2 * NKF) + kf) * 512 + l * 8;
    *(uint4*)&F[ohi] = ph;
    *(uint4*)&F[ohi + (size_t)NKF * 512] = pl;
}

// ---------------- all weight + embedding conversions in ONE launch ----------------
__global__ __launch_bounds__(256) void k_cvt_all(const float* __restrict__ emb,
                                                 const float* __restrict__ w_in,
                                                 const float* __restrict__ w_out,
                                                 ushort* __restrict__ embf,
                                                 ushort* __restrict__ wfi0,
                                                 ushort* __restrict__ wfi1,
                                                 ushort* __restrict__ wfo0,
                                                 ushort* __restrict__ wfo1) {
    const int bid = blockIdx.x;
    const int tid = threadIdx.x;
    if (bid < 128) {
        cvt_w_body(w_in, wfi0, 2 * DINNER, DMODEL / 32, bid * 256 + tid);
    } else if (bid < 256) {
        cvt_w_body(w_in + (size_t)DMODEL * 2 * DINNER, wfi1, 2 * DINNER, DMODEL / 32,
                   (bid - 128) * 256 + tid);
    } else if (bid < 320) {
        cvt_w_body(w_out, wfo0, DMODEL, DINNER / 32, (bid - 256) * 256 + tid);
    } else if (bid < 384) {
        cvt_w_body(w_out + (size_t)DINNER * DMODEL, wfo1, DMODEL, DINNER / 32,
                   (bid - 320) * 256 + tid);
    } else {
        const int idx = (bid - 384) * 256 + tid;   // 0..16383
        const int v  = idx >> 6;
        const int c0 = (idx & 63) * 4;
        float4 sv = *(const float4*)&emb[(size_t)v * DMODEL + c0];
        float s[4] = {sv.x, sv.y, sv.z, sv.w};
        unsigned hi[4], lo[4];
#pragma unroll
        for (int j = 0; j < 4; ++j) {
            hi[j] = f2bf(s[j]);
            lo[j] = f2bf(s[j] - bf2f(hi[j]));
        }
        *(uint2*)&embf[(size_t)v * 512 + c0] =
            make_uint2(hi[0] | (hi[1] << 16), hi[2] | (hi[3] << 16));
        *(uint2*)&embf[(size_t)v * 512 + 256 + c0] =
            make_uint2(lo[0] | (lo[1] << 16), lo[2] | (lo[3] << 16));
    }
}

// ---------------- bf16 MFMA GEMM: A row-major bf16 [M][KE] (per-lane gather), B frag ----------------
template<int SPLITK, bool IDS>
__global__ __launch_bounds__(256) void k_mgemm(const ushort* __restrict__ A,
                                               const ushort* __restrict__ Bf,
                                               float* __restrict__ C,
                                               int M, int N, int KE,
                                               const int* __restrict__ ids) {
    __shared__ __align__(16) ushort As[8 * 512];
    __shared__ __align__(16) ushort Bs[8 * 512];
    const int tid = threadIdx.x;
    const int w = tid >> 6, lane = tid & 63;
    const int n0 = blockIdx.x * 128, m0 = blockIdx.y * 128;
    const int nkf = KE >> 5;
    const int KT = nkf / SPLITK;
    const int kt0 = blockIdx.z * KT;
    const int wm = w & 1, wn = w >> 1;
    const int c0 = 2 * w, c1 = c0 + 1;

    f32x4 acc[4][4] = {};

    int row0 = m0 + c0 * 16 + (lane & 15);
    int row1 = m0 + c1 * 16 + (lane & 15);
    if (IDS) { row0 = ids[row0]; row1 = ids[row1]; }
    const ushort* Ap0 = A + (size_t)row0 * KE + (lane >> 4) * 8;
    const ushort* Ap1 = A + (size_t)row1 * KE + (lane >> 4) * 8;
    const ushort* Bb0 = Bf + ((size_t)(n0 / 16 + c0) * nkf) * 512 + lane * 8;
    const ushort* Bb1 = Bf + ((size_t)(n0 / 16 + c1) * nkf) * 512 + lane * 8;
    ushort* As0 = As + c0 * 512 + lane * 8;
    ushort* As1 = As + c1 * 512 + lane * 8;
    ushort* Bs0 = Bs + c0 * 512 + lane * 8;
    ushort* Bs1 = Bs + c1 * 512 + lane * 8;

    for (int kt = kt0; kt < kt0 + KT; ++kt) {
        __builtin_amdgcn_global_load_lds((const __attribute__((address_space(1))) void*)(Ap0 + kt * 32),
                                         (__attribute__((address_space(3))) void*)As0, 16, 0, 0);
        __builtin_amdgcn_global_load_lds((const __attribute__((address_space(1))) void*)(Ap1 + kt * 32),
                                         (__attribute__((address_space(3))) void*)As1, 16, 0, 0);
        __builtin_amdgcn_global_load_lds((const __attribute__((address_space(1))) void*)(Bb0 + (size_t)kt * 512),
                                         (__attribute__((address_space(3))) void*)Bs0, 16, 0, 0);
        __builtin_amdgcn_global_load_lds((const __attribute__((address_space(1))) void*)(Bb1 + (size_t)kt * 512),
                                         (__attribute__((address_space(3))) void*)Bs1, 16, 0, 0);
        __syncthreads();
        short8 av[4], bv[4];
#pragma unroll
        for (int i = 0; i < 4; ++i)
            av[i] = *(const short8*)&As[(wm * 4 + i) * 512 + lane * 8];
#pragma unroll
        for (int i = 0; i < 4; ++i)
            bv[i] = *(const short8*)&Bs[(wn * 4 + i) * 512 + lane * 8];
#pragma unroll
        for (int mi = 0; mi < 4; ++mi)
#pragma unroll
            for (int ni = 0; ni < 4; ++ni)
                acc[mi][ni] = __builtin_amdgcn_mfma_f32_16x16x32_bf16(av[mi], bv[ni],
                                                                      acc[mi][ni], 0, 0, 0);
        __syncthreads();
    }

    // C/D layout (m89-verified): col = lane&15, row = (lane>>4)*4 + reg
    float* Cw = C + (size_t)blockIdx.z * ((size_t)M * N);
    const int r0 = (lane >> 4) * 4, cc = lane & 15;
#pragma unroll
    for (int mi = 0; mi < 4; ++mi)
#pragma unroll
        for (int r = 0; r < 4; ++r) {
            const int row = m0 + wm * 64 + mi * 16 + r0 + r;
            float* crow = &Cw[(size_t)row * N + n0 + wn * 64 + cc];
#pragma unroll
            for (int ni = 0; ni < 4; ++ni) crow[ni * 16] = acc[mi][ni][r];
        }
}

// sum 4 M*N slabs; TOBF: write bf16 hi|lo row-major [BL][2*DMODEL] instead of fp32
template<bool TOBF>
__global__ __launch_bounds__(256) void k_red4(const float* __restrict__ p,
                                              float* __restrict__ o,
                                              ushort* __restrict__ xb, int n4) {
    int i = blockIdx.x * 256 + threadIdx.x;
    const float4* p4 = (const float4*)p;
    float4 a = p4[i], b = p4[i + n4], c = p4[i + 2 * n4], d = p4[i + 3 * n4];
    float4 r = make_float4(a.x + b.x + c.x + d.x, a.y + b.y + c.y + d.y,
                           a.z + b.z + c.z + d.z, a.w + b.w + c.w + d.w);
    if (TOBF) {
        const int e0 = i * 4;
        const int bl = e0 >> 8;
        const int cl = e0 & 255;
        float s[4] = {r.x, r.y, r.z, r.w};
        unsigned hi[4], lo[4];
#pragma unroll
        for (int j = 0; j < 4; ++j) {
            hi[j] = f2bf(s[j]);
            lo[j] = f2bf(s[j] - bf2f(hi[j]));
        }
        *(uint2*)&xb[(size_t)bl * 512 + cl] =
            make_uint2(hi[0] | (hi[1] << 16), hi[2] | (hi[3] << 16));
        *(uint2*)&xb[(size_t)bl * 512 + 256 + cl] =
            make_uint2(lo[0] | (lo[1] << 16), lo[2] | (lo[3] << 16));
    } else {
        ((float4*)o)[i] = r;
    }
}

// ---------------- fused conv+SiLU + x_proj + delta (round-10 body, measured 38.7 us) ----------------
__global__ __launch_bounds__(256) void k_xpd(const float* __restrict__ xz,
                                             const float* __restrict__ cw,
                                             const float* __restrict__ cb,
                                             const float* __restrict__ w_xp,
                                             const float* __restrict__ w_dt,
                                             const float* __restrict__ b_dt,
                                             float* __restrict__ u,
                                             float* __restrict__ Bm,
                                             float* __restrict__ Cm,
                                             float* __restrict__ delta) {
    const int tid = threadIdx.x;
    const int bl0 = blockIdx.x * 16;
    __shared__ float us[16 * DINNER];   // 32 KB
    __shared__ float wsx[128 * 48];     // 24 KB (one chunk of w_xp)
    __shared__ float dts[16][DTRANK];   // 1 KB

    // ---- phase 0: conv + SiLU for 16 tokens (each thread: channels tid, tid+256)
    {
        const int ch0 = tid, ch1 = 256 + tid;
        float4 cwA = *(const float4*)&cw[ch0 * 4];
        float4 cwB = *(const float4*)&cw[ch1 * 4];
        const float cbA = cb[ch0], cbB = cb[ch1];
        const int lbase = bl0 & (LL - 1);
#pragma unroll
        for (int m = 0; m < 16; ++m) {
            const int bl = bl0 + m;
            const int lpos = lbase + m;
            float aA = cbA, aB = cbB;
#pragma unroll
            for (int k = 0; k < DCONV; ++k) {
                int tt = lpos - (DCONV - 1) + k;
                if (tt >= 0) {
                    const float* xr = &xz[(size_t)(bl - (DCONV - 1) + k) * 2 * DINNER];
                    aA = fmaf(((const float*)&cwA)[k], xr[ch0], aA);
                    aB = fmaf(((const float*)&cwB)[k], xr[ch1], aB);
                }
            }
            float uA = aA * sigmoidf_(aA);
            float uB = aB * sigmoidf_(aB);
            us[m * DINNER + ch0] = uA;
            us[m * DINNER + ch1] = uB;
            u[(size_t)bl * DINNER + ch0] = uA;
            u[(size_t)bl * DINNER + ch1] = uB;
        }
    }

    const int mp = tid >> 5;
    const int jg = (tid >> 3) & 3;
    const int s  = tid & 7;
    const float* usm0 = &us[(mp * 2 + 0) * DINNER];
    const float* usm1 = &us[(mp * 2 + 1) * DINNER];

    float acc0[12] = {}, acc1[12] = {};
#pragma unroll 1
    for (int ck = 0; ck < 4; ++ck) {
        __syncthreads();   // us ready (ck=0); wsx consumers done (ck>0)
        {   // stage w_xp rows [ck*128, ck*128+128): 1536 float4
            const float4* wg = (const float4*)&w_xp[ck * 128 * 48];
            float4* wl = (float4*)wsx;
#pragma unroll
            for (int q = 0; q < 6; ++q) wl[tid + q * 256] = wg[tid + q * 256];
        }
        __syncthreads();
#pragma unroll
        for (int i = 0; i < 16; ++i) {
            const int kl = i * 8 + s;
            const float a0 = usm0[ck * 128 + kl];
            const float a1 = usm1[ck * 128 + kl];
            const float* wr = &wsx[kl * 48 + jg * 12];
            float4 w0 = *(const float4*)&wr[0];
            float4 w1 = *(const float4*)&wr[4];
            float4 w2 = *(const float4*)&wr[8];
            acc0[0]  = fmaf(a0, w0.x, acc0[0]);  acc1[0]  = fmaf(a1, w0.x, acc1[0]);
            acc0[1]  = fmaf(a0, w0.y, acc0[1]);  acc1[1]  = fmaf(a1, w0.y, acc1[1]);
            acc0[2]  = fmaf(a0, w0.z, acc0[2]);  acc1[2]  = fmaf(a1, w0.z, acc1[2]);
            acc0[3]  = fmaf(a0, w0.w, acc0[3]);  acc1[3]  = fmaf(a1, w0.w, acc1[3]);
            acc0[4]  = fmaf(a0, w1.x, acc0[4]);  acc1[4]  = fmaf(a1, w1.x, acc1[4]);
            acc0[5]  = fmaf(a0, w1.y, acc0[5]);  acc1[5]  = fmaf(a1, w1.y, acc1[5]);
            acc0[6]  = fmaf(a0, w1.z, acc0[6]);  acc1[6]  = fmaf(a1, w1.z, acc1[6]);
            acc0[7]  = fmaf(a0, w1.w, acc0[7]);  acc1[7]  = fmaf(a1, w1.w, acc1[7]);
            acc0[8]  = fmaf(a0, w2.x, acc0[8]);  acc1[8]  = fmaf(a1, w2.x, acc1[8]);
            acc0[9]  = fmaf(a0, w2.y, acc0[9]);  acc1[9]  = fmaf(a1, w2.y, acc1[9]);
            acc0[10] = fmaf(a0, w2.z, acc0[10]); acc1[10] = fmaf(a1, w2.z, acc1[10]);
            acc0[11] = fmaf(a0, w2.w, acc0[11]); acc1[11] = fmaf(a1, w2.w, acc1[11]);
        }
    }
    // butterfly reduce across the 8 k-slice lanes
#pragma unroll
    for (int off = 4; off >= 1; off >>= 1) {
#pragma unroll
        for (int j = 0; j < 12; ++j) {
            acc0[j] += __shfl_xor(acc0[j], off, 8);
            acc1[j] += __shfl_xor(acc1[j], off, 8);
        }
    }
    if (s < 6) {
        const int bl_a = bl0 + mp * 2 + 0;
        const int bl_b = bl0 + mp * 2 + 1;
#pragma unroll
        for (int q = 0; q < 2; ++q) {
            int j = jg * 12 + s * 2 + q;
            float v0 = acc0[s * 2 + q];
            float v1 = acc1[s * 2 + q];
            if (j < 16) {
                dts[mp * 2 + 0][j] = v0;
                dts[mp * 2 + 1][j] = v1;
            } else if (j < 32) {
                Bm[(size_t)bl_a * DSTATE + (j - 16)] = v0;
                Bm[(size_t)bl_b * DSTATE + (j - 16)] = v1;
            } else {
                Cm[(size_t)bl_a * DSTATE + (j - 32)] = v0;
                Cm[(size_t)bl_b * DSTATE + (j - 32)] = v1;
            }
        }
    }
    __syncthreads();

    // phase 2: delta = softplus(dt @ w_dt + b_dt); thread: 4 channels x 8 tokens
    const int c0 = (tid & 127) * 4;
    const int mb = (tid >> 7) * 8;
    float4 bd = *(const float4*)&b_dt[c0];
    float a0[8], a1[8], a2[8], a3[8];
#pragma unroll
    for (int t = 0; t < 8; ++t) { a0[t] = bd.x; a1[t] = bd.y; a2[t] = bd.z; a3[t] = bd.w; }
#pragma unroll
    for (int r = 0; r < DTRANK; ++r) {
        float4 w4 = *(const float4*)&w_dt[r * DINNER + c0];
#pragma unroll
        for (int t = 0; t < 8; ++t) {
            float f = dts[mb + t][r];
            a0[t] = fmaf(f, w4.x, a0[t]);
            a1[t] = fmaf(f, w4.y, a1[t]);
            a2[t] = fmaf(f, w4.z, a2[t]);
            a3[t] = fmaf(f, w4.w, a3[t]);
        }
    }
#pragma unroll
    for (int t = 0; t < 8; ++t) {
        float4 o;
        o.x = (a0[t] > 20.f) ? a0[t] : log1pf(__expf(a0[t]));
        o.y = (a1[t] > 20.f) ? a1[t] : log1pf(__expf(a1[t]));
        o.z = (a2[t] > 20.f) ? a2[t] : log1pf(__expf(a2[t]));
        o.w = (a3[t] > 20.f) ? a3[t] : log1pf(__expf(a3[t]));
        *(float4*)&delta[(size_t)(bl0 + mb + t) * DINNER + c0] = o;
    }
}

// ---------------- chunked selective scan, per-channel 16-state-in-registers ----------------
__global__ __launch_bounds__(256) void k_scan_a(const float* __restrict__ delta,
                                                const float* __restrict__ u,
                                                const float* __restrict__ Bm,
                                                const float* __restrict__ A_log,
                                                float* __restrict__ aprod,
                                                float* __restrict__ hend) {
    const int tid = threadIdx.x;
    const int bid = blockIdx.x;
    const int chalf = bid & 1;
    const int k = (bid >> 1) & (NCHUNK - 1);
    const int b = bid >> 7;
    const int c = chalf * 256 + tid;
    const int bl0 = b * LL + k * LC;

    __shared__ float Bs[LC * DSTATE];
    for (int i = tid; i < LC * DSTATE; i += 256) Bs[i] = Bm[(size_t)bl0 * DSTATE + i];
    __syncthreads();

    float Ac[DSTATE];
#pragma unroll
    for (int q = 0; q < 4; ++q) {
        float4 a = *(const float4*)&A_log[c * DSTATE + q * 4];
        Ac[q * 4 + 0] = -__expf(a.x); Ac[q * 4 + 1] = -__expf(a.y);
        Ac[q * 4 + 2] = -__expf(a.z); Ac[q * 4 + 3] = -__expf(a.w);
    }

    float h[DSTATE] = {};
    float ap[DSTATE];
#pragma unroll
    for (int n = 0; n < DSTATE; ++n) ap[n] = 1.f;

    float dlt = delta[(size_t)bl0 * DINNER + c];
    float uu  = u[(size_t)bl0 * DINNER + c];
    for (int t = 0; t < LC; ++t) {
        float dlt2 = 0.f, uu2 = 0.f;
        if (t + 1 < LC) {
            dlt2 = delta[(size_t)(bl0 + t + 1) * DINNER + c];
            uu2  = u[(size_t)(bl0 + t + 1) * DINNER + c];
        }
        const float w = dlt * uu;
        const float4* Bs4 = (const float4*)&Bs[t * DSTATE];
        float4 b0 = Bs4[0], b1 = Bs4[1], b2 = Bs4[2], b3 = Bs4[3];
        float bv[DSTATE] = {b0.x, b0.y, b0.z, b0.w, b1.x, b1.y, b1.z, b1.w,
                            b2.x, b2.y, b2.z, b2.w, b3.x, b3.y, b3.z, b3.w};
#pragma unroll
        for (int n = 0; n < DSTATE; ++n) {
            float dA = __expf(dlt * Ac[n]);
            ap[n] *= dA;
            h[n] = fmaf(dA, h[n], w * bv[n]);
        }
        dlt = dlt2; uu = uu2;
    }
    size_t base = ((size_t)(k * BB + b) * DINNER + c) * DSTATE;
#pragma unroll
    for (int q = 0; q < 4; ++q) {
        *(float4*)&aprod[base + q * 4] = make_float4(ap[q*4], ap[q*4+1], ap[q*4+2], ap[q*4+3]);
        *(float4*)&hend[base + q * 4]  = make_float4(h[q*4],  h[q*4+1],  h[q*4+2],  h[q*4+3]);
    }
}

__global__ __launch_bounds__(256) void k_scan_b(const float* __restrict__ aprod,
                                                const float* __restrict__ hend,
                                                float* __restrict__ hstart) {
    int i = blockIdx.x * 256 + threadIdx.x;
    float h = 0.f;
#pragma unroll 4
    for (int k = 0; k < NCHUNK; ++k) {
        size_t idx = (size_t)k * NREC + i;
        float a = aprod[idx];
        float e = hend[idx];
        hstart[idx] = h;
        h = fmaf(a, h, e);
    }
}

// Pass C: re-scan chunk, emit gated output as bf16 hi|lo row-major [BL][2*DINNER]
__global__ __launch_bounds__(256) void k_scan_c(const float* __restrict__ delta,
                                                const float* __restrict__ u,
                                                const float* __restrict__ xz,
                                                const float* __restrict__ Bm,
                                                const float* __restrict__ Cm,
                                                const float* __restrict__ A_log,
                                                const float* __restrict__ Dp,
                                                const float* __restrict__ hstart,
                                                ushort* __restrict__ yb) {
    const int tid = threadIdx.x;
    const int bid = blockIdx.x;
    const int chalf = bid & 1;
    const int k = (bid >> 1) & (NCHUNK - 1);
    const int b = bid >> 7;
    const int c = chalf * 256 + tid;
    const int bl0 = b * LL + k * LC;

    __shared__ float Bs[LC * DSTATE];
    __shared__ float Cs[LC * DSTATE];
    for (int i = tid; i < LC * DSTATE; i += 256) {
        Bs[i] = Bm[(size_t)bl0 * DSTATE + i];
        Cs[i] = Cm[(size_t)bl0 * DSTATE + i];
    }
    __syncthreads();

    float Ac[DSTATE];
#pragma unroll
    for (int q = 0; q < 4; ++q) {
        float4 a = *(const float4*)&A_log[c * DSTATE + q * 4];
        Ac[q * 4 + 0] = -__expf(a.x); Ac[q * 4 + 1] = -__expf(a.y);
        Ac[q * 4 + 2] = -__expf(a.z); Ac[q * 4 + 3] = -__expf(a.w);
    }
    const float Dc = Dp[c];

    float h[DSTATE];
    size_t hbase = ((size_t)(k * BB + b) * DINNER + c) * DSTATE;
#pragma unroll
    for (int q = 0; q < 4; ++q) {
        float4 hv = *(const float4*)&hstart[hbase + q * 4];
        h[q*4] = hv.x; h[q*4+1] = hv.y; h[q*4+2] = hv.z; h[q*4+3] = hv.w;
    }

    float dlt = delta[(size_t)bl0 * DINNER + c];
    float uu  = u[(size_t)bl0 * DINNER + c];
    float rr  = xz[(size_t)bl0 * 2 * DINNER + DINNER + c];
    for (int t = 0; t < LC; ++t) {
        float dlt2 = 0.f, uu2 = 0.f, rr2 = 0.f;
        if (t + 1 < LC) {
            dlt2 = delta[(size_t)(bl0 + t + 1) * DINNER + c];
            uu2  = u[(size_t)(bl0 + t + 1) * DINNER + c];
            rr2  = xz[(size_t)(bl0 + t + 1) * 2 * DINNER + DINNER + c];
        }
        const float w = dlt * uu;
        const float4* Bs4 = (const float4*)&Bs[t * DSTATE];
        float4 b0 = Bs4[0], b1 = Bs4[1], b2 = Bs4[2], b3 = Bs4[3];
        float bv[DSTATE] = {b0.x, b0.y, b0.z, b0.w, b1.x, b1.y, b1.z, b1.w,
                            b2.x, b2.y, b2.z, b2.w, b3.x, b3.y, b3.z, b3.w};
        const float4* Cs4 = (const float4*)&Cs[t * DSTATE];
        float4 c0 = Cs4[0], c1 = Cs4[1], c2 = Cs4[2], c3 = Cs4[3];
        float cv[DSTATE] = {c0.x, c0.y, c0.z, c0.w, c1.x, c1.y, c1.z, c1.w,
                            c2.x, c2.y, c2.z, c2.w, c3.x, c3.y, c3.z, c3.w};
        float s0 = 0.f, s1 = 0.f, s2 = 0.f, s3 = 0.f;
#pragma unroll
        for (int n = 0; n < DSTATE; n += 4) {
            float dA0 = __expf(dlt * Ac[n+0]);
            float dA1 = __expf(dlt * Ac[n+1]);
            float dA2 = __expf(dlt * Ac[n+2]);
            float dA3 = __expf(dlt * Ac[n+3]);
            h[n+0] = fmaf(dA0, h[n+0], w * bv[n+0]);
            h[n+1] = fmaf(dA1, h[n+1], w * bv[n+1]);
            h[n+2] = fmaf(dA2, h[n+2], w * bv[n+2]);
            h[n+3] = fmaf(dA3, h[n+3], w * bv[n+3]);
            s0 = fmaf(h[n+0], cv[n+0], s0);
            s1 = fmaf(h[n+1], cv[n+1], s1);
            s2 = fmaf(h[n+2], cv[n+2], s2);
            s3 = fmaf(h[n+3], cv[n+3], s3);
        }
        float yv = (s0 + s1) + (s2 + s3) + uu * Dc;
        float yg = yv * (rr * sigmoidf_(rr));
        unsigned hi = f2bf(yg);
        unsigned lo = f2bf(yg - bf2f(hi));
        yb[(size_t)(bl0 + t) * (2 * DINNER) + c] = (ushort)hi;
        yb[(size_t)(bl0 + t) * (2 * DINNER) + DINNER + c] = (ushort)lo;
        dlt = dlt2; uu = uu2; rr = rr2;
    }
}

extern "C" void kernel_launch(void* const* d_in, const int* in_sizes, int n_in,
                              void* d_out, int out_size, void* d_ws, size_t ws_size,
                              hipStream_t stream) {
    const int*   ids   = (const int*)d_in[0];
    const float* emb   = (const float*)d_in[1];
    const float* w_in  = (const float*)d_in[2];
    const float* cw    = (const float*)d_in[3];
    const float* cb    = (const float*)d_in[4];
    const float* w_xp  = (const float*)d_in[5];
    const float* w_dt  = (const float*)d_in[6];
    const float* b_dt  = (const float*)d_in[7];
    const float* A_log = (const float*)d_in[8];
    const float* Dp    = (const float*)d_in[9];
    const float* w_out = (const float*)d_in[10];
    float* out = (float*)d_out;

    float* ws = (float*)d_ws;
    float* x    = ws;                              // BL*256  floats (xb bf16 / aprod overlay)
    float* xz   = x  + (size_t)BL * DMODEL;        // BL*1024 (also split-K partials)
    float* u    = xz + (size_t)BL * 2 * DINNER;    // BL*512
    float* Bm   = u  + (size_t)BL * DINNER;        // BL*16
    float* Cm   = Bm + (size_t)BL * DSTATE;        // BL*16
    float* dlt  = Cm + (size_t)BL * DSTATE;        // BL*512
    float* y    = dlt + (size_t)BL * DINNER;       // BL*512 floats = yb bf16 [BL][1024]
    float* hend = y + (size_t)BL * DINNER;         // NCHUNK*NREC = 2.10M
    float* wfi0f = hend + (size_t)NCHUNK * NREC;   // 262144 floats (w_in frag l0)
    float* wfi1f = wfi0f + 262144;                 // 262144 floats (w_in frag l1)
    float* wfo0f = wfi1f + 262144;                 // 131072 floats (w_out frag l0)
    float* wfo1f = wfo0f + 131072;                 // 131072 floats (w_out frag l1)
    float* embff = wfo1f + 131072;                 // 65536 floats (emb bf16 table)
    float* aprod  = x;
    float* hstart = aprod;
    ushort* xb   = (ushort*)x;      // [BL][512] hi|lo, written by red4<true> (layer 0)
    ushort* yb   = (ushort*)y;      // [BL][1024] hi|lo, written by scan_c
    ushort* wfi[2] = {(ushort*)wfi0f, (ushort*)wfi1f};
    ushort* wfo[2] = {(ushort*)wfo0f, (ushort*)wfo1f};
    ushort* embf = (ushort*)embff;  // [VOCAB][512] hi|lo

    // all weight + embedding conversions in one launch
    k_cvt_all<<<448, 256, 0, stream>>>(emb, w_in, w_out, embf,
                                       wfi[0], wfi[1], wfo[0], wfo[1]);

    for (int l = 0; l < NLAYER; ++l) {
        // ---- in_proj: xz = A @ w_in via split-bf16 MFMA (row-major A, per-lane gather)
        if (l == 0)
            k_mgemm<1, true><<<dim3(2 * DINNER / 128, BL / 128, 1), 256, 0, stream>>>(
                embf, wfi[0], xz, BL, 2 * DINNER, 2 * DMODEL, ids);
        else
            k_mgemm<1, false><<<dim3(2 * DINNER / 128, BL / 128, 1), 256, 0, stream>>>(
                xb, wfi[1], xz, BL, 2 * DINNER, 2 * DMODEL, ids);

        // ---- fused conv+silu + x_proj + delta (r10 body)
        k_xpd<<<BL / 16, 256, 0, stream>>>(xz, cw + l * DINNER * DCONV, cb + l * DINNER,
                                           w_xp + (size_t)l * DINNER * 48,
                                           w_dt + (size_t)l * DTRANK * DINNER,
                                           b_dt + (size_t)l * DINNER, u, Bm, Cm, dlt);

        const float* Al = A_log + (size_t)l * DINNER * DSTATE;
        k_scan_a<<<BB * NCHUNK * 2, 256, 0, stream>>>(dlt, u, Bm, Al, aprod, hend);
        k_scan_b<<<NREC / 256, 256, 0, stream>>>(aprod, hend, hstart);
        k_scan_c<<<BB * NCHUNK * 2, 256, 0, stream>>>(dlt, u, xz, Bm, Cm, Al,
                                                      Dp + (size_t)l * DINNER, hstart, yb);

        // ---- out_proj: dst = y @ w_out via split-bf16 MFMA, split-K=4 into xz
        k_mgemm<4, false><<<dim3(DMODEL / 128, BL / 128, 4), 256, 0, stream>>>(
            yb, wfo[l], xz, BL, DMODEL, 2 * DINNER, ids);
        if (l == NLAYER - 1)
            k_red4<false><<<(BL * DMODEL / 4) / 256, 256, 0, stream>>>(xz, out, xb,
                                                                       BL * DMODEL / 4);
        else
            k_red4<true><<<(BL * DMODEL / 4) / 256, 256, 0, stream>>>(xz, out, xb,
                                                                      BL * DMODEL / 4);
    }
}